// Round 14
// baseline (900.067 us; speedup 1.0000x reference)
//
#include <hip/hip_runtime.h>
#include <math.h>

#define N_NODES  100000
#define N_HEDGES 50000
#define HPAD     50176    // 196 * 256
#define N_INC    300000
#define N_GRAPHS 1024
#define D_IN     49
#define D        512
#define NPAD     100096   // 391 * 256
#define KPAD_IN  64

typedef __attribute__((ext_vector_type(8))) short short8;
typedef __attribute__((ext_vector_type(8))) __bf16 bf16x8;
typedef __attribute__((ext_vector_type(4))) float f32x4;

__device__ __forceinline__ short f2bf(float f) {
    union { float f; unsigned u; } v; v.f = f;
    unsigned r = v.u + 0x7fffu + ((v.u >> 16) & 1u);
    return (short)(r >> 16);
}
__device__ __forceinline__ float bf2f(short s) {
    union { unsigned u; float f; } v; v.u = ((unsigned)(unsigned short)s) << 16;
    return v.f;
}

__device__ __forceinline__ void gld16(const void* g, void* l) {
    __builtin_amdgcn_global_load_lds(
        (const __attribute__((address_space(1))) unsigned int*)g,
        (__attribute__((address_space(3))) unsigned int*)l, 16, 0, 0);
}

// ---------------- GEMM: C[M,512] = A[M,K](bf16) @ Bt[512,K](bf16), flexible epilogues --------------
// 256x128 tile, 8 waves (512 thr). global_load_lds(16B) staging, pre-swizzled source (conflict-free
// ds_read_b128). 2-buffer + COUNTED vmcnt(3): stage(t+2) issued after barrier#2 into the buffer
// just read; tile t+1's loads stay in flight across both barriers (never drain to 0 mid-loop).
// 48KB LDS -> 3 blocks/CU preserved. Builtin MFMA.
// FAST bf16 epilogue (Cbf && !Cf && !CbfT): per-wave LDS transpose -> coalesced 16B/lane stores.
__global__ __launch_bounds__(512) void gemm_bf16(
    const short* __restrict__ A, const short* __restrict__ Bt,
    const float* __restrict__ bias,
    short* __restrict__ Cbf, float* __restrict__ Cf, short* __restrict__ CbfT, int strideT,
    const int* __restrict__ hcnt, const int* __restrict__ htypes,
    const float* __restrict__ tembW2, const float* __restrict__ bb,
    int K, int nby, int layerWGs, long aStr, long bStr, long cStr)
{
    __shared__ short lds[24576];          // As: 2x256x32 @0 ; Bs: 2x128x32 @16384 ; epilogue overlay @0
    const int tid  = threadIdx.x;
    const int lane = tid & 63;
    const int wave = tid >> 6;      // 0..7
    const int wr = wave >> 1;       // 0..3
    const int wc = wave & 1;        // 0..1

    // bijective XCD-aware swizzle (m204)
    const int nwg = gridDim.x;
    const int q8 = nwg >> 3, r8 = nwg & 7;
    const int xcd = blockIdx.x & 7, loc = blockIdx.x >> 3;
    int wg = (xcd < r8) ? (xcd * (q8 + 1) + loc) : (r8 * (q8 + 1) + (xcd - r8) * q8 + loc);
    if (layerWGs) {
        const int layer = wg / layerWGs;
        wg %= layerWGs;
        A += layer * aStr;
        Bt += layer * bStr;
        if (CbfT) CbfT += layer * cStr;
    }
    const long row0 = (long)(wg / nby) * 256;
    const int  col0 = (wg % nby) * 128;

    f32x4 acc[4][4];
    #pragma unroll
    for (int m = 0; m < 4; m++)
        #pragma unroll
        for (int n = 0; n < 4; n++)
            acc[m][n] = (f32x4)(0.0f);

    const int ch   = lane & 3;
    const int rofs = lane >> 2;
    const short* aSrc[2];
    const short* bSrc;
    #pragma unroll
    for (int j = 0; j < 2; j++) {
        const int rloc = (wave * 2 + j) * 16 + rofs;      // 0..255
        const int sw = (rloc >> 1) & 3;
        aSrc[j] = A + (row0 + rloc) * (long)K + (ch ^ sw) * 8;
    }
    {
        const int rlb = wave * 16 + rofs;                 // 0..127
        const int swb = (rlb >> 1) & 3;
        bSrc = Bt + ((long)col0 + rlb) * K + (ch ^ swb) * 8;
    }

    const int ks = lane >> 4;
    const int rl = lane & 15;
    const int nk = K >> 5;

    // prologue: stage tile 0 -> buf0, tile 1 -> buf1 (3 gld16 per wave per tile)
    gld16(aSrc[0], &lds[(wave * 2) * 16 * 32]);
    gld16(aSrc[1], &lds[(wave * 2 + 1) * 16 * 32]);
    gld16(bSrc,    &lds[16384 + wave * 16 * 32]);
    if (nk > 1) {
        gld16(aSrc[0] + 32, &lds[8192 + (wave * 2) * 16 * 32]);
        gld16(aSrc[1] + 32, &lds[8192 + (wave * 2 + 1) * 16 * 32]);
        gld16(bSrc    + 32, &lds[16384 + 4096 + wave * 16 * 32]);
    }

    for (int t = 0; t < nk; t++) {
        if (t + 1 < nk) asm volatile("s_waitcnt vmcnt(3)" ::: "memory");   // my tile-t loads landed
        else            asm volatile("s_waitcnt vmcnt(0)" ::: "memory");
        __builtin_amdgcn_s_barrier();            // all waves' tile-t loads landed
        __builtin_amdgcn_sched_barrier(0);
        const int cb = t & 1;
        bf16x8 a[4], b[4];
        #pragma unroll
        for (int m = 0; m < 4; m++) {
            const int rr = wr * 64 + m * 16 + rl;
            a[m] = *(const bf16x8*)&lds[cb * 8192 + rr * 32 + (ks ^ ((rr >> 1) & 3)) * 8];
        }
        #pragma unroll
        for (int n = 0; n < 4; n++) {
            const int rr = wc * 64 + n * 16 + rl;
            b[n] = *(const bf16x8*)&lds[16384 + cb * 4096 + rr * 32 + (ks ^ ((rr >> 1) & 3)) * 8];
        }
        #pragma unroll
        for (int m = 0; m < 4; m++)
            #pragma unroll
            for (int n = 0; n < 4; n++)
                acc[m][n] = __builtin_amdgcn_mfma_f32_16x16x32_bf16(a[m], b[n], acc[m][n], 0, 0, 0);
        __builtin_amdgcn_sched_barrier(0);
        __builtin_amdgcn_s_barrier();            // all waves done reading buf[cb]
        if (t + 2 < nk) {                        // refill buf[cb] with tile t+2; stays in flight
            gld16(aSrc[0] + (t + 2) * 32, &lds[cb * 8192 + (wave * 2) * 16 * 32]);
            gld16(aSrc[1] + (t + 2) * 32, &lds[cb * 8192 + (wave * 2 + 1) * 16 * 32]);
            gld16(bSrc    + (t + 2) * 32, &lds[16384 + cb * 4096 + wave * 16 * 32]);
        }
    }

    const int rl2 = lane & 15;
    if (Cbf && !Cf && !CbfT) {
        // ---- FAST epilogue: column constants in registers, LDS transpose, coalesced b128 stores ----
        float bbv[4], tw0[4], tw1[4], tw2[4], biv[4];
        #pragma unroll
        for (int n = 0; n < 4; n++) {
            const int col = col0 + wc * 64 + n * 16 + rl2;
            if (hcnt) {
                bbv[n] = bb[col];
                tw0[n] = tembW2[col];
                tw1[n] = tembW2[D + col];
                tw2[n] = tembW2[2 * D + col];
            } else {
                biv[n] = bias ? bias[col] : 0.0f;
            }
        }
        short* ep = &lds[wave * 2304];        // 32 rows x 72 shorts per wave
        #pragma unroll
        for (int p = 0; p < 2; p++) {
            #pragma unroll
            for (int mm = 0; mm < 2; mm++) {
                const int m = 2 * p + mm;
                #pragma unroll
                for (int rr = 0; rr < 4; rr++) {
                    const long row = row0 + wr * 64 + m * 16 + (lane >> 4) * 4 + rr;
                    const int  lr  = mm * 16 + (lane >> 4) * 4 + rr;
                    if (hcnt) {
                        const float cf  = (float)hcnt[row];
                        const float icf = 1.0f / fmaxf(cf, 1.0f);
                        const int ty = (row < N_HEDGES) ? htypes[row] : 0;
                        #pragma unroll
                        for (int n = 0; n < 4; n++) {
                            float tsel = (ty == 0) ? tw0[n] : (ty == 1) ? tw1[n] : tw2[n];
                            float v = (acc[m][n][rr] + cf * bbv[n]) * icf + tsel;
                            ep[lr * 72 + n * 16 + rl2] = f2bf(v);
                        }
                    } else {
                        #pragma unroll
                        for (int n = 0; n < 4; n++) {
                            float v = acc[m][n][rr] + biv[n];
                            ep[lr * 72 + n * 16 + rl2] = f2bf(v);
                        }
                    }
                }
            }
            __syncthreads();
            #pragma unroll
            for (int i = 0; i < 4; i++) {
                const int lr2 = i * 8 + (lane >> 3);
                const int c2  = lane & 7;
                short8 vv = *(const short8*)&ep[lr2 * 72 + c2 * 8];
                const long row = row0 + wr * 64 + p * 32 + lr2;
                *(short8*)&Cbf[row * D + col0 + wc * 64 + c2 * 8] = vv;
            }
            __syncthreads();
        }
    } else {
        // ---- generic epilogue (small dispatches: f32 out, transposed out) ----
        const int rb4 = wr * 64 + (lane >> 4) * 4;
        #pragma unroll
        for (int m = 0; m < 4; m++) {
            #pragma unroll
            for (int n = 0; n < 4; n++) {
                const int col = col0 + wc * 64 + n * 16 + rl2;
                const float bi = bias ? bias[col] : 0.0f;
                #pragma unroll
                for (int rr = 0; rr < 4; rr++) {
                    const long row = row0 + rb4 + m * 16 + rr;
                    float v = acc[m][n][rr];
                    if (hcnt) {
                        const float cf = (float)hcnt[row];
                        const int ty = (row < N_HEDGES) ? htypes[row] : 0;
                        v = (v + cf * bb[col]) * (1.0f / fmaxf(cf, 1.0f)) + tembW2[(long)ty * D + col];
                    } else {
                        v += bi;
                    }
                    if (Cbf)  Cbf[row * D + col] = f2bf(v);
                    if (Cf)   Cf[row * D + col]  = v;
                    if (CbfT && row < strideT) CbfT[(long)col * strideT + row] = f2bf(v);
                }
            }
        }
    }
}

// ---------------- degree counts ----------------
__global__ void count_inc_kernel(const int* __restrict__ nidx, const int* __restrict__ hidx,
                                 int* cnt_n, int* cnt_h) {
    int i = blockIdx.x * 256 + threadIdx.x;
    if (i < N_INC) {
        atomicAdd(&cnt_h[hidx[i]], 1);
        atomicAdd(&cnt_n[nidx[i]], 1);
    }
}

// ---------------- hierarchical exclusive scan (3 phases, 2048 elems/block) ----------------
__global__ __launch_bounds__(256) void scan1_kernel(const int* __restrict__ cnt, int* __restrict__ out,
                                                    int* __restrict__ bsum, int n) {
    __shared__ int s[256];
    const int t = threadIdx.x;
    const long base = (long)blockIdx.x * 2048 + t * 8;
    int v[8];
    int ts = 0;
    #pragma unroll
    for (int j = 0; j < 8; j++) {
        v[j] = (base + j < n) ? cnt[base + j] : 0;
        ts += v[j];
    }
    s[t] = ts;
    __syncthreads();
    for (int ofs = 1; ofs < 256; ofs <<= 1) {
        int x = (t >= ofs) ? s[t - ofs] : 0;
        __syncthreads();
        s[t] += x;
        __syncthreads();
    }
    int run = (t == 0) ? 0 : s[t - 1];
    #pragma unroll
    for (int j = 0; j < 8; j++) {
        if (base + j < n) out[base + j] = run;
        run += v[j];
    }
    if (t == 255) bsum[blockIdx.x] = s[255];
}

__global__ __launch_bounds__(256) void scan2_kernel(int* __restrict__ bsum, int nb, int* __restrict__ total) {
    __shared__ int s[256];
    const int t = threadIdx.x;
    int v = (t < nb) ? bsum[t] : 0;
    s[t] = v;
    __syncthreads();
    for (int ofs = 1; ofs < 256; ofs <<= 1) {
        int x = (t >= ofs) ? s[t - ofs] : 0;
        __syncthreads();
        s[t] += x;
        __syncthreads();
    }
    if (t < nb) bsum[t] = (t == 0) ? 0 : s[t - 1];
    if (t == 255) *total = s[255];
}

__global__ __launch_bounds__(256) void scan3_kernel(int* __restrict__ out, const int* __restrict__ bsum, int n) {
    const int add = bsum[blockIdx.x];
    if (add == 0) return;
    const long base = (long)blockIdx.x * 2048 + threadIdx.x * 8;
    #pragma unroll
    for (int j = 0; j < 8; j++)
        if (base + j < n) out[base + j] += add;
}

// CSR placement via atomic cursors
__global__ void place_kernel(const int* __restrict__ nidx, const int* __restrict__ hidx,
                             const int* __restrict__ hoff, const int* __restrict__ noff,
                             int* hcur, int* ncur, int* __restrict__ hlist, int* __restrict__ nlist) {
    int e = blockIdx.x * 256 + threadIdx.x;
    if (e < N_INC) {
        int h = hidx[e], n = nidx[e];
        int p = atomicAdd(&hcur[h], 1);
        hlist[hoff[h] + p] = n;
        int q = atomicAdd(&ncur[n], 1);
        nlist[noff[n] + q] = h;
    }
}

// ---------------- weight transpose+convert: W[K,512] f32 -> Wt[512,Kpad] bf16 ----------------
__global__ void wtrans_kernel(const float* __restrict__ W, short* __restrict__ Wt, int K, int Kpad) {
    int n = blockIdx.x;
    for (int k = threadIdx.x; k < Kpad; k += 64)
        Wt[(long)n * Kpad + k] = (k < K) ? f2bf(W[(long)k * D + n]) : (short)0;
}

// batched l2w transpose: 3 layers in one dispatch (grid 3*D)
__global__ void wtrans3_kernel(const float* __restrict__ W, short* __restrict__ Wt) {
    int layer = blockIdx.x >> 9;           // /512
    int n = blockIdx.x & 511;
    const float* src = W + (size_t)layer * D * D;
    short* dst = Wt + (size_t)layer * D * D;
    for (int k = threadIdx.x; k < D; k += 64)
        dst[(long)n * D + k] = f2bf(src[(long)k * D + n]);
}

// plain f32 -> bf16 convert (8/thread)
__global__ void cvt_f32_bf16_kernel(const float* __restrict__ src, short* __restrict__ dst) {
    long i = ((long)blockIdx.x * 256 + threadIdx.x) * 8;
    float4 f0 = *(const float4*)(src + i);
    float4 f1 = *(const float4*)(src + i + 4);
    short8 o;
    o[0] = f2bf(f0.x); o[1] = f2bf(f0.y); o[2] = f2bf(f0.z); o[3] = f2bf(f0.w);
    o[4] = f2bf(f1.x); o[5] = f2bf(f1.y); o[6] = f2bf(f1.z); o[7] = f2bf(f1.w);
    *(short8*)(dst + i) = o;
}

// W[rows,512] f32 -> dst[256,512] bf16, zero-padding rows >= rows_real
__global__ void cvt_w_pad_kernel(const float* __restrict__ src, short* __restrict__ dst, int rows_real) {
    int r = blockIdx.x;           // 0..255
    int c = threadIdx.x * 8;
    short8 o = (short8)0;
    if (r < rows_real) {
        float4 f0 = *(const float4*)(src + (long)r * D + c);
        float4 f1 = *(const float4*)(src + (long)r * D + c + 4);
        o[0] = f2bf(f0.x); o[1] = f2bf(f0.y); o[2] = f2bf(f0.z); o[3] = f2bf(f0.w);
        o[4] = f2bf(f1.x); o[5] = f2bf(f1.y); o[6] = f2bf(f1.z); o[7] = f2bf(f1.w);
    }
    *(short8*)(dst + (long)r * D + c) = o;
}

// vecmat: out[col] = sum_j v[j] * M[j*512+col]
__global__ __launch_bounds__(256) void vecmat_kernel(const float* __restrict__ v,
                                                     const float* __restrict__ M,
                                                     float* __restrict__ out) {
    int col = blockIdx.x * 256 + threadIdx.x;
    float a = 0.f;
    for (int j = 0; j < D; j++) a += v[j] * M[(long)j * D + col];
    out[col] = a;
}

__global__ void vecadd_kernel(const float* __restrict__ a, const float* __restrict__ b,
                              float* __restrict__ o) {
    int i = blockIdx.x * 256 + threadIdx.x;
    o[i] = a[i] + b[i];
}

// batched TB precompute: grid 6 (3 layers x 2 col-halves). TB[layer][4][512]
__global__ __launch_bounds__(256) void smallmm3_kernel(
    const float* __restrict__ temb, const float* __restrict__ l1b,
    const float* __restrict__ l2w, float* __restrict__ TB)
{
    int layer = blockIdx.x >> 1;
    int col = (blockIdx.x & 1) * 256 + threadIdx.x;
    const float* b1 = l1b + (size_t)layer * D;
    const float* W2 = l2w + (size_t)layer * D * D;
    float a0 = 0.f, a1 = 0.f, a2 = 0.f, a3 = 0.f;
    for (int j = 0; j < D; j++) {
        float w = W2[(long)j * D + col];
        a0 += temb[j] * w;
        a1 += temb[D + j] * w;
        a2 += temb[2 * D + j] * w;
        a3 += b1[j] * w;
    }
    float* o = TB + (size_t)layer * 4 * D;
    o[col] = a0; o[D + col] = a1; o[2 * D + col] = a2; o[3 * D + col] = a3;
}

// node_features [N,49] f32 -> A0 [NPAD,64] bf16 (zero pad)
__global__ void cvt_in_kernel(const float* __restrict__ nf, short* __restrict__ A0) {
    int r = blockIdx.x;
    int c = threadIdx.x;
    short v = 0;
    if (r < N_NODES && c < D_IN) v = f2bf(nf[(long)r * D_IN + c]);
    A0[(long)r * KPAD_IN + c] = v;
}

// hedge pre-sum, 512 cols (unrolled x2 gather): hs[e,:] = sum_{members} x[n,:]
__global__ __launch_bounds__(256) void hedge_sum_kernel(
    const short* __restrict__ x, const int* __restrict__ hoff, const int* __restrict__ hlist,
    short* __restrict__ hs)
{
    int row = blockIdx.x * 4 + (threadIdx.x >> 6);      // grid = HPAD/4
    int lane = threadIdx.x & 63;
    float acc[8] = {0, 0, 0, 0, 0, 0, 0, 0};
    if (row < N_HEDGES) {
        int s = hoff[row], e = hoff[row + 1];
        int j = s;
        for (; j + 1 < e; j += 2) {
            short8 v0 = *(const short8*)(x + (long)hlist[j] * D + lane * 8);
            short8 v1 = *(const short8*)(x + (long)hlist[j + 1] * D + lane * 8);
            #pragma unroll
            for (int k = 0; k < 8; k++) acc[k] += bf2f(v0[k]) + bf2f(v1[k]);
        }
        if (j < e) {
            short8 v0 = *(const short8*)(x + (long)hlist[j] * D + lane * 8);
            #pragma unroll
            for (int k = 0; k < 8; k++) acc[k] += bf2f(v0[k]);
        }
    }
    short8 o;
    #pragma unroll
    for (int k = 0; k < 8; k++) o[k] = f2bf(acc[k]);
    *(short8*)(hs + (long)row * D + lane * 8) = o;
}

// hedge pre-sum, 64 cols (layer-0 input features)
__global__ __launch_bounds__(256) void hedge_sum64_kernel(
    const short* __restrict__ A0, const int* __restrict__ hoff, const int* __restrict__ hlist,
    short* __restrict__ hs0)
{
    int row = blockIdx.x * 4 + (threadIdx.x >> 6);      // grid = HPAD/4
    int c = threadIdx.x & 63;
    float acc = 0.f;
    if (row < N_HEDGES) {
        int s = hoff[row], e = hoff[row + 1];
        int j = s;
        for (; j + 1 < e; j += 2) {
            float a = bf2f(A0[(long)hlist[j] * KPAD_IN + c]);
            float b = bf2f(A0[(long)hlist[j + 1] * KPAD_IN + c]);
            acc += a + b;
        }
        if (j < e) acc += bf2f(A0[(long)hlist[j] * KPAD_IN + c]);
    }
    hs0[(long)row * KPAD_IN + c] = f2bf(acc);
}

// fused node gather + residual + bias + LayerNorm + GELU.
// If outf == null: writes bf16 into x (in place). If outf != null: writes ONLY f32 outf.
__global__ __launch_bounds__(256) void node_ln_gelu_kernel(
    const short* __restrict__ hmsg, const int* __restrict__ noff, const int* __restrict__ nlist,
    short* __restrict__ x, const float* __restrict__ b2,
    const float* __restrict__ g, const float* __restrict__ b, float* __restrict__ outf)
{
    const int row = blockIdx.x * 4 + (threadIdx.x >> 6);
    const int lane = threadIdx.x & 63;
    int s = noff[row], e = noff[row + 1];
    float acc[8] = {0, 0, 0, 0, 0, 0, 0, 0};
    int j = s;
    for (; j + 1 < e; j += 2) {
        short8 v0 = *(const short8*)(hmsg + (long)nlist[j] * D + lane * 8);
        short8 v1 = *(const short8*)(hmsg + (long)nlist[j + 1] * D + lane * 8);
        #pragma unroll
        for (int k = 0; k < 8; k++) acc[k] += bf2f(v0[k]) + bf2f(v1[k]);
    }
    if (j < e) {
        short8 v0 = *(const short8*)(hmsg + (long)nlist[j] * D + lane * 8);
        #pragma unroll
        for (int k = 0; k < 8; k++) acc[k] += bf2f(v0[k]);
    }
    const float inv = 1.0f / fmaxf((float)(e - s), 1.0f);
    short8 xv = *(const short8*)(x + (long)row * D + lane * 8);
    const float4 c0 = *(const float4*)(b2 + lane * 8);
    const float4 c1 = *(const float4*)(b2 + lane * 8 + 4);
    const float cv[8] = {c0.x, c0.y, c0.z, c0.w, c1.x, c1.y, c1.z, c1.w};
    float f[8];
    float sum = 0.f, sq = 0.f;
    #pragma unroll
    for (int k = 0; k < 8; k++) {
        f[k] = acc[k] * inv + bf2f(xv[k]) + cv[k];
        sum += f[k]; sq += f[k] * f[k];
    }
    #pragma unroll
    for (int o = 32; o > 0; o >>= 1) { sum += __shfl_xor(sum, o, 64); sq += __shfl_xor(sq, o, 64); }
    const float mean = sum * (1.0f / D);
    const float var  = sq * (1.0f / D) - mean * mean;
    const float rstd = rsqrtf(var + 1e-5f);
    const float4 g0 = *(const float4*)(g + lane * 8);
    const float4 g1 = *(const float4*)(g + lane * 8 + 4);
    const float4 b0 = *(const float4*)(b + lane * 8);
    const float4 b1 = *(const float4*)(b + lane * 8 + 4);
    const float gv[8] = {g0.x, g0.y, g0.z, g0.w, g1.x, g1.y, g1.z, g1.w};
    const float bv[8] = {b0.x, b0.y, b0.z, b0.w, b1.x, b1.y, b1.z, b1.w};
    float yout[8];
    #pragma unroll
    for (int k = 0; k < 8; k++) {
        float y = (f[k] - mean) * rstd * gv[k] + bv[k];
        yout[k] = 0.5f * y * (1.0f + erff(y * 0.70710678118654752f));
    }
    if (outf) {
        float4 o0 = {yout[0], yout[1], yout[2], yout[3]};
        float4 o1 = {yout[4], yout[5], yout[6], yout[7]};
        *(float4*)(outf + (long)row * D + lane * 8) = o0;
        *(float4*)(outf + (long)row * D + lane * 8 + 4) = o1;
    } else {
        short8 o8;
        #pragma unroll
        for (int k = 0; k < 8; k++) o8[k] = f2bf(yout[k]);
        *(short8*)(x + (long)row * D + lane * 8) = o8;
    }
}

// graph pooling via sorted batch segments (f32 in, bf16 out)
__global__ __launch_bounds__(64) void pool_kernel(const float* __restrict__ x, const int* __restrict__ batch,
                                                  short* __restrict__ Gbf) {
    int g = blockIdx.x;
    int lo = 0, hi = N_NODES;
    while (lo < hi) { int mid = (lo + hi) >> 1; if (batch[mid] < g) lo = mid + 1; else hi = mid; }
    int s = lo;
    hi = N_NODES;
    while (lo < hi) { int mid = (lo + hi) >> 1; if (batch[mid] < g + 1) lo = mid + 1; else hi = mid; }
    int e = lo;
    int lane = threadIdx.x;
    float acc[8] = {0, 0, 0, 0, 0, 0, 0, 0};
    for (int r = s; r < e; r++) {
        const float* rp = x + (long)r * D + lane * 8;
        float4 v0 = *(const float4*)rp;
        float4 v1 = *(const float4*)(rp + 4);
        acc[0] += v0.x; acc[1] += v0.y; acc[2] += v0.z; acc[3] += v0.w;
        acc[4] += v1.x; acc[5] += v1.y; acc[6] += v1.z; acc[7] += v1.w;
    }
    float inv = 1.0f / fmaxf((float)(e - s), 1.0f);
    short8 o;
    #pragma unroll
    for (int k = 0; k < 8; k++) o[k] = f2bf(acc[k] * inv);
    *(short8*)(Gbf + (long)g * D + lane * 8) = o;
}

__global__ void batchf_kernel(const int* __restrict__ batch, float* __restrict__ ob) {
    int i = blockIdx.x * 256 + threadIdx.x;
    if (i < N_NODES) ob[i] = (float)batch[i];
}

extern "C" void kernel_launch(void* const* d_in, const int* in_sizes, int n_in,
                              void* d_out, int out_size, void* d_ws, size_t ws_size,
                              hipStream_t stream) {
    (void)in_sizes; (void)n_in; (void)out_size; (void)ws_size;
    const float* nf    = (const float*)d_in[0];
    const int*   nidx  = (const int*)d_in[1];
    const int*   hidx  = (const int*)d_in[2];
    const int*   htype = (const int*)d_in[3];
    const int*   batch = (const int*)d_in[4];
    const float* in_w  = (const float*)d_in[6];
    const float* in_b  = (const float*)d_in[7];
    const float* temb  = (const float*)d_in[8];
    const float* l1w   = (const float*)d_in[9];
    const float* l1b   = (const float*)d_in[10];
    const float* l2w   = (const float*)d_in[11];
    const float* l2b   = (const float*)d_in[12];
    const float* lng   = (const float*)d_in[13];
    const float* lnb   = (const float*)d_in[14];
    const float* outw  = (const float*)d_in[15];
    const float* outb  = (const float*)d_in[16];

    float* out_graph = (float*)d_out;                       // [1024,512]
    float* out_nodes = out_graph + (long)N_GRAPHS * D;      // [100000,512]
    float* out_batch = out_nodes + (long)N_NODES * D;       // [100000]

    char* wsb = (char*)d_ws;
    size_t off = 0;
    auto alloc = [&](size_t bytes) {
        void* p = wsb + off;
        off += (bytes + 255) & ~(size_t)255;
        return p;
    };
    short* x_bf  = (short*)alloc((size_t)NPAD * D * 2);
    short* hs_bf = (short*)alloc((size_t)HPAD * D * 2);
    short* h_bf  = (short*)alloc((size_t)HPAD * D * 2);
    short* hs0   = (short*)alloc((size_t)HPAD * KPAD_IN * 2);
    short* G_bf  = (short*)alloc((size_t)N_GRAPHS * D * 2);
    short* A0    = (short*)alloc((size_t)NPAD * KPAD_IN * 2);
    short* wt    = (short*)alloc((size_t)D * D * 2);
    short* wt3   = (short*)alloc((size_t)3 * D * D * 2);
    short* w1bf  = (short*)alloc((size_t)3 * D * D * 2);
    short* W12t  = (short*)alloc((size_t)3 * D * D * 2);
    short* inwbf = (short*)alloc((size_t)256 * D * 2);
    short* M0t   = (short*)alloc((size_t)D * KPAD_IN * 2);
    float* TB    = (float*)alloc((size_t)3 * 4 * D * 4);
    float* tmpv  = (float*)alloc((size_t)D * 4);
    float* bias0 = (float*)alloc((size_t)D * 4);
    float* bb0   = (float*)alloc((size_t)D * 4);
    int* cnt_h   = (int*)alloc((size_t)HPAD * 4);
    int* cnt_n   = (int*)alloc((size_t)N_NODES * 4);
    int* hoff    = (int*)alloc((size_t)(N_HEDGES + 1) * 4);
    int* noff    = (int*)alloc((size_t)(N_NODES + 1) * 4);
    int* hcur    = (int*)alloc((size_t)N_HEDGES * 4);
    int* ncur    = (int*)alloc((size_t)N_NODES * 4);
    int* hlist   = (int*)alloc((size_t)N_INC * 4);
    int* nlist   = (int*)alloc((size_t)N_INC * 4);
    int* bsum    = (int*)alloc((size_t)256 * 4);

    // ---- build CSR (both directions) ----
    hipMemsetAsync(cnt_h, 0, (size_t)HPAD * 4, stream);
    hipMemsetAsync(cnt_n, 0, (size_t)N_NODES * 4, stream);
    hipMemsetAsync(hcur,  0, (size_t)N_HEDGES * 4, stream);
    hipMemsetAsync(ncur,  0, (size_t)N_NODES * 4, stream);
    count_inc_kernel<<<(N_INC + 255) / 256, 256, 0, stream>>>(nidx, hidx, cnt_n, cnt_h);
    const int NBH = (N_HEDGES + 2047) / 2048;
    const int NBN = (N_NODES + 2047) / 2048;
    scan1_kernel<<<NBH, 256, 0, stream>>>(cnt_h, hoff, bsum, N_HEDGES);
    scan2_kernel<<<1, 256, 0, stream>>>(bsum, NBH, hoff + N_HEDGES);
    scan3_kernel<<<NBH, 256, 0, stream>>>(hoff, bsum, N_HEDGES);
    scan1_kernel<<<NBN, 256, 0, stream>>>(cnt_n, noff, bsum, N_NODES);
    scan2_kernel<<<1, 256, 0, stream>>>(bsum, NBN, noff + N_NODES);
    scan3_kernel<<<NBN, 256, 0, stream>>>(noff, bsum, N_NODES);
    place_kernel<<<(N_INC + 255) / 256, 256, 0, stream>>>(nidx, hidx, hoff, noff, hcur, ncur, hlist, nlist);
    batchf_kernel<<<(N_NODES + 255) / 256, 256, 0, stream>>>(batch, out_batch);

    // ---- weight precompute (batched): W12t[i] = (l1_w[i] @ l2_w[i])^T ; TB[i] ----
    cvt_f32_bf16_kernel<<<(3 * D * D / 8) / 256, 256, 0, stream>>>(l1w, w1bf);
    wtrans3_kernel<<<3 * D, 64, 0, stream>>>(l2w, wt3);
    gemm_bf16<<<24, 512, 0, stream>>>(w1bf, wt3, nullptr, nullptr, nullptr, W12t, D,
                                      nullptr, nullptr, nullptr, nullptr, D, 4,
                                      8, (long)D * D, (long)D * D, (long)D * D);
    smallmm3_kernel<<<6, 256, 0, stream>>>(temb, l1b, l2w, TB);

    // ---- layer-0 shortcut: M0t = (in_w @ W12[0])^T (K=64-packed); bb0 = bias0 + b1W2_0 ----
    cvt_w_pad_kernel<<<256, 64, 0, stream>>>(in_w, inwbf, D_IN);
    gemm_bf16<<<4, 512, 0, stream>>>(inwbf, W12t, nullptr, nullptr, nullptr, M0t, KPAD_IN,
                                     nullptr, nullptr, nullptr, nullptr, D, 4, 0, 0, 0, 0);
    vecmat_kernel<<<2, 256, 0, stream>>>(in_b, l1w, tmpv);
    vecmat_kernel<<<2, 256, 0, stream>>>(tmpv, l2w, bias0);
    vecadd_kernel<<<2, 256, 0, stream>>>(bias0, TB + 3 * D, bb0);

    // ---- input projection: x_bf = bf16(nf @ in_w + in_b) ----
    wtrans_kernel<<<D, 64, 0, stream>>>(in_w, wt, D_IN, KPAD_IN);
    cvt_in_kernel<<<NPAD, 64, 0, stream>>>(nf, A0);
    const int NWG  = (NPAD / 256) * 4;   // 1564
    const int NWGH = (HPAD / 256) * 4;   // 784
    gemm_bf16<<<NWG, 512, 0, stream>>>(A0, wt, in_b, x_bf, nullptr, nullptr, 0,
                                       nullptr, nullptr, nullptr, nullptr, KPAD_IN, 4, 0, 0, 0, 0);

    for (int i = 0; i < 3; i++) {
        // hedge pre-sum (Ah·x), then hedge-space GEMM with fused message epilogue
        if (i == 0) {
            hedge_sum64_kernel<<<HPAD / 4, 256, 0, stream>>>(A0, hoff, hlist, hs0);
            gemm_bf16<<<NWGH, 512, 0, stream>>>(hs0, M0t, nullptr, h_bf, nullptr, nullptr, 0,
                                                cnt_h, htype, TB, bb0, KPAD_IN, 4, 0, 0, 0, 0);
        } else {
            hedge_sum_kernel<<<HPAD / 4, 256, 0, stream>>>(x_bf, hoff, hlist, hs_bf);
            gemm_bf16<<<NWGH, 512, 0, stream>>>(hs_bf, W12t + (size_t)i * D * D, nullptr,
                                                h_bf, nullptr, nullptr, 0,
                                                cnt_h, htype, TB + (size_t)i * 4 * D,
                                                TB + (size_t)i * 4 * D + 3 * D, D, 4, 0, 0, 0, 0);
        }
        // x = gelu(LN(segsum(h)/clip + x + b2)); last layer writes ONLY f32 out_nodes
        node_ln_gelu_kernel<<<N_NODES / 4, 256, 0, stream>>>(h_bf, noff, nlist, x_bf,
                                                             l2b + (size_t)i * D,
                                                             lng + (size_t)i * D, lnb + (size_t)i * D,
                                                             (i < 2) ? nullptr : out_nodes);
    }

    // ---- graph pooling (reads f32 out_nodes) + output projection ----
    pool_kernel<<<N_GRAPHS, 64, 0, stream>>>(out_nodes, batch, G_bf);
    wtrans_kernel<<<D, 64, 0, stream>>>(outw, wt, D, D);
    gemm_bf16<<<(N_GRAPHS / 256) * 4, 512, 0, stream>>>(G_bf, wt, outb, nullptr, out_graph, nullptr, 0,
                                                        nullptr, nullptr, nullptr, nullptr, D, 4, 0, 0, 0, 0);
}

// Round 15
// 887.024 us; speedup vs baseline: 1.0147x; 1.0147x over previous
//
#include <hip/hip_runtime.h>
#include <math.h>

#define N_NODES  100000
#define N_HEDGES 50000
#define HPAD     50176    // 196 * 256
#define N_INC    300000
#define N_GRAPHS 1024
#define D_IN     49
#define D        512
#define NPAD     100096   // 391 * 256
#define KPAD_IN  64

typedef __attribute__((ext_vector_type(8))) short short8;
typedef __attribute__((ext_vector_type(8))) __bf16 bf16x8;
typedef __attribute__((ext_vector_type(4))) float f32x4;

__device__ __forceinline__ short f2bf(float f) {
    union { float f; unsigned u; } v; v.f = f;
    unsigned r = v.u + 0x7fffu + ((v.u >> 16) & 1u);
    return (short)(r >> 16);
}
__device__ __forceinline__ float bf2f(short s) {
    union { unsigned u; float f; } v; v.u = ((unsigned)(unsigned short)s) << 16;
    return v.f;
}

// fast tanh-form GELU: 0.5y(1+tanh(0.79788456(y+0.044715y^3))) = y*u/(1+u), u=e^{2t}
// |err| <= ~1e-3 absolute (threshold is 20.48; current absmax 0.09) — ~11 VALU ops vs erff's ~30+.
__device__ __forceinline__ float fast_gelu(float y) {
    const float y2 = y * y;
    const float p  = fmaf(y2, 0.0356774081f, 0.7978845608f);  // 0.79788456*(1+0.044715*y^2)
    float arg = y * p * 2.8853900818f;                        // 2t*log2(e)
    arg = fminf(fmaxf(arg, -30.0f), 30.0f);
    const float u = __builtin_exp2f(arg);
    return y * u * __builtin_amdgcn_rcpf(1.0f + u);
}

__device__ __forceinline__ void gld16(const void* g, void* l) {
    __builtin_amdgcn_global_load_lds(
        (const __attribute__((address_space(1))) unsigned int*)g,
        (__attribute__((address_space(3))) unsigned int*)l, 16, 0, 0);
}

// ---------------- GEMM: C[M,512] = A[M,K](bf16) @ Bt[512,K](bf16), flexible epilogues --------------
// 256x128 tile, 8 waves (512 thr). global_load_lds(16B) staging, pre-swizzled source (conflict-free
// ds_read_b128). 2-buffer + counted vmcnt(3). 48KB LDS -> 3 blocks/CU. Builtin MFMA.
// FAST bf16 epilogue (Cbf && !Cf && !CbfT): per-wave LDS transpose -> coalesced 16B/lane stores.
__global__ __launch_bounds__(512) void gemm_bf16(
    const short* __restrict__ A, const short* __restrict__ Bt,
    const float* __restrict__ bias,
    short* __restrict__ Cbf, float* __restrict__ Cf, short* __restrict__ CbfT, int strideT,
    const int* __restrict__ hcnt, const int* __restrict__ htypes,
    const float* __restrict__ tembW2, const float* __restrict__ bb,
    int K, int nby, int layerWGs, long aStr, long bStr, long cStr)
{
    __shared__ short lds[24576];          // As: 2x256x32 @0 ; Bs: 2x128x32 @16384 ; epilogue overlay @0
    const int tid  = threadIdx.x;
    const int lane = tid & 63;
    const int wave = tid >> 6;      // 0..7
    const int wr = wave >> 1;       // 0..3
    const int wc = wave & 1;        // 0..1

    // bijective XCD-aware swizzle (m204)
    const int nwg = gridDim.x;
    const int q8 = nwg >> 3, r8 = nwg & 7;
    const int xcd = blockIdx.x & 7, loc = blockIdx.x >> 3;
    int wg = (xcd < r8) ? (xcd * (q8 + 1) + loc) : (r8 * (q8 + 1) + (xcd - r8) * q8 + loc);
    if (layerWGs) {
        const int layer = wg / layerWGs;
        wg %= layerWGs;
        A += layer * aStr;
        Bt += layer * bStr;
        if (CbfT) CbfT += layer * cStr;
    }
    const long row0 = (long)(wg / nby) * 256;
    const int  col0 = (wg % nby) * 128;

    f32x4 acc[4][4];
    #pragma unroll
    for (int m = 0; m < 4; m++)
        #pragma unroll
        for (int n = 0; n < 4; n++)
            acc[m][n] = (f32x4)(0.0f);

    const int ch   = lane & 3;
    const int rofs = lane >> 2;
    const short* aSrc[2];
    const short* bSrc;
    #pragma unroll
    for (int j = 0; j < 2; j++) {
        const int rloc = (wave * 2 + j) * 16 + rofs;      // 0..255
        const int sw = (rloc >> 1) & 3;
        aSrc[j] = A + (row0 + rloc) * (long)K + (ch ^ sw) * 8;
    }
    {
        const int rlb = wave * 16 + rofs;                 // 0..127
        const int swb = (rlb >> 1) & 3;
        bSrc = Bt + ((long)col0 + rlb) * K + (ch ^ swb) * 8;
    }

    const int ks = lane >> 4;
    const int rl = lane & 15;
    const int nk = K >> 5;

    // prologue: stage tile 0 -> buf0, tile 1 -> buf1 (3 gld16 per wave per tile)
    gld16(aSrc[0], &lds[(wave * 2) * 16 * 32]);
    gld16(aSrc[1], &lds[(wave * 2 + 1) * 16 * 32]);
    gld16(bSrc,    &lds[16384 + wave * 16 * 32]);
    if (nk > 1) {
        gld16(aSrc[0] + 32, &lds[8192 + (wave * 2) * 16 * 32]);
        gld16(aSrc[1] + 32, &lds[8192 + (wave * 2 + 1) * 16 * 32]);
        gld16(bSrc    + 32, &lds[16384 + 4096 + wave * 16 * 32]);
    }

    for (int t = 0; t < nk; t++) {
        if (t + 1 < nk) asm volatile("s_waitcnt vmcnt(3)" ::: "memory");   // my tile-t loads landed
        else            asm volatile("s_waitcnt vmcnt(0)" ::: "memory");
        __builtin_amdgcn_s_barrier();            // all waves' tile-t loads landed
        __builtin_amdgcn_sched_barrier(0);
        const int cb = t & 1;
        bf16x8 a[4], b[4];
        #pragma unroll
        for (int m = 0; m < 4; m++) {
            const int rr = wr * 64 + m * 16 + rl;
            a[m] = *(const bf16x8*)&lds[cb * 8192 + rr * 32 + (ks ^ ((rr >> 1) & 3)) * 8];
        }
        #pragma unroll
        for (int n = 0; n < 4; n++) {
            const int rr = wc * 64 + n * 16 + rl;
            b[n] = *(const bf16x8*)&lds[16384 + cb * 4096 + rr * 32 + (ks ^ ((rr >> 1) & 3)) * 8];
        }
        #pragma unroll
        for (int m = 0; m < 4; m++)
            #pragma unroll
            for (int n = 0; n < 4; n++)
                acc[m][n] = __builtin_amdgcn_mfma_f32_16x16x32_bf16(a[m], b[n], acc[m][n], 0, 0, 0);
        __builtin_amdgcn_sched_barrier(0);
        __builtin_amdgcn_s_barrier();            // all waves done reading buf[cb]
        if (t + 2 < nk) {                        // refill buf[cb] with tile t+2; stays in flight
            gld16(aSrc[0] + (t + 2) * 32, &lds[cb * 8192 + (wave * 2) * 16 * 32]);
            gld16(aSrc[1] + (t + 2) * 32, &lds[cb * 8192 + (wave * 2 + 1) * 16 * 32]);
            gld16(bSrc    + (t + 2) * 32, &lds[16384 + cb * 4096 + wave * 16 * 32]);
        }
    }

    const int rl2 = lane & 15;
    if (Cbf && !Cf && !CbfT) {
        // ---- FAST epilogue: column constants in registers, LDS transpose, coalesced b128 stores ----
        float bbv[4], tw0[4], tw1[4], tw2[4], biv[4];
        #pragma unroll
        for (int n = 0; n < 4; n++) {
            const int col = col0 + wc * 64 + n * 16 + rl2;
            if (hcnt) {
                bbv[n] = bb[col];
                tw0[n] = tembW2[col];
                tw1[n] = tembW2[D + col];
                tw2[n] = tembW2[2 * D + col];
            } else {
                biv[n] = bias ? bias[col] : 0.0f;
            }
        }
        short* ep = &lds[wave * 2304];        // 32 rows x 72 shorts per wave
        #pragma unroll
        for (int p = 0; p < 2; p++) {
            #pragma unroll
            for (int mm = 0; mm < 2; mm++) {
                const int m = 2 * p + mm;
                #pragma unroll
                for (int rr = 0; rr < 4; rr++) {
                    const long row = row0 + wr * 64 + m * 16 + (lane >> 4) * 4 + rr;
                    const int  lr  = mm * 16 + (lane >> 4) * 4 + rr;
                    if (hcnt) {
                        const float cf  = (float)hcnt[row];
                        const float icf = 1.0f / fmaxf(cf, 1.0f);
                        const int ty = (row < N_HEDGES) ? htypes[row] : 0;
                        #pragma unroll
                        for (int n = 0; n < 4; n++) {
                            float tsel = (ty == 0) ? tw0[n] : (ty == 1) ? tw1[n] : tw2[n];
                            float v = (acc[m][n][rr] + cf * bbv[n]) * icf + tsel;
                            ep[lr * 72 + n * 16 + rl2] = f2bf(v);
                        }
                    } else {
                        #pragma unroll
                        for (int n = 0; n < 4; n++) {
                            float v = acc[m][n][rr] + biv[n];
                            ep[lr * 72 + n * 16 + rl2] = f2bf(v);
                        }
                    }
                }
            }
            __syncthreads();
            #pragma unroll
            for (int i = 0; i < 4; i++) {
                const int lr2 = i * 8 + (lane >> 3);
                const int c2  = lane & 7;
                short8 vv = *(const short8*)&ep[lr2 * 72 + c2 * 8];
                const long row = row0 + wr * 64 + p * 32 + lr2;
                *(short8*)&Cbf[row * D + col0 + wc * 64 + c2 * 8] = vv;
            }
            __syncthreads();
        }
    } else {
        // ---- generic epilogue (small dispatches: f32 out, transposed out) ----
        const int rb4 = wr * 64 + (lane >> 4) * 4;
        #pragma unroll
        for (int m = 0; m < 4; m++) {
            #pragma unroll
            for (int n = 0; n < 4; n++) {
                const int col = col0 + wc * 64 + n * 16 + rl2;
                const float bi = bias ? bias[col] : 0.0f;
                #pragma unroll
                for (int rr = 0; rr < 4; rr++) {
                    const long row = row0 + rb4 + m * 16 + rr;
                    float v = acc[m][n][rr];
                    if (hcnt) {
                        const float cf = (float)hcnt[row];
                        const int ty = (row < N_HEDGES) ? htypes[row] : 0;
                        v = (v + cf * bb[col]) * (1.0f / fmaxf(cf, 1.0f)) + tembW2[(long)ty * D + col];
                    } else {
                        v += bi;
                    }
                    if (Cbf)  Cbf[row * D + col] = f2bf(v);
                    if (Cf)   Cf[row * D + col]  = v;
                    if (CbfT && row < strideT) CbfT[(long)col * strideT + row] = f2bf(v);
                }
            }
        }
    }
}

// ---------------- degree counts ----------------
__global__ void count_inc_kernel(const int* __restrict__ nidx, const int* __restrict__ hidx,
                                 int* cnt_n, int* cnt_h) {
    int i = blockIdx.x * 256 + threadIdx.x;
    if (i < N_INC) {
        atomicAdd(&cnt_h[hidx[i]], 1);
        atomicAdd(&cnt_n[nidx[i]], 1);
    }
}

// ---------------- hierarchical exclusive scan (3 phases, 2048 elems/block) ----------------
__global__ __launch_bounds__(256) void scan1_kernel(const int* __restrict__ cnt, int* __restrict__ out,
                                                    int* __restrict__ bsum, int n) {
    __shared__ int s[256];
    const int t = threadIdx.x;
    const long base = (long)blockIdx.x * 2048 + t * 8;
    int v[8];
    int ts = 0;
    #pragma unroll
    for (int j = 0; j < 8; j++) {
        v[j] = (base + j < n) ? cnt[base + j] : 0;
        ts += v[j];
    }
    s[t] = ts;
    __syncthreads();
    for (int ofs = 1; ofs < 256; ofs <<= 1) {
        int x = (t >= ofs) ? s[t - ofs] : 0;
        __syncthreads();
        s[t] += x;
        __syncthreads();
    }
    int run = (t == 0) ? 0 : s[t - 1];
    #pragma unroll
    for (int j = 0; j < 8; j++) {
        if (base + j < n) out[base + j] = run;
        run += v[j];
    }
    if (t == 255) bsum[blockIdx.x] = s[255];
}

__global__ __launch_bounds__(256) void scan2_kernel(int* __restrict__ bsum, int nb, int* __restrict__ total) {
    __shared__ int s[256];
    const int t = threadIdx.x;
    int v = (t < nb) ? bsum[t] : 0;
    s[t] = v;
    __syncthreads();
    for (int ofs = 1; ofs < 256; ofs <<= 1) {
        int x = (t >= ofs) ? s[t - ofs] : 0;
        __syncthreads();
        s[t] += x;
        __syncthreads();
    }
    if (t < nb) bsum[t] = (t == 0) ? 0 : s[t - 1];
    if (t == 255) *total = s[255];
}

__global__ __launch_bounds__(256) void scan3_kernel(int* __restrict__ out, const int* __restrict__ bsum, int n) {
    const int add = bsum[blockIdx.x];
    if (add == 0) return;
    const long base = (long)blockIdx.x * 2048 + threadIdx.x * 8;
    #pragma unroll
    for (int j = 0; j < 8; j++)
        if (base + j < n) out[base + j] += add;
}

// CSR placement via atomic cursors
__global__ void place_kernel(const int* __restrict__ nidx, const int* __restrict__ hidx,
                             const int* __restrict__ hoff, const int* __restrict__ noff,
                             int* hcur, int* ncur, int* __restrict__ hlist, int* __restrict__ nlist) {
    int e = blockIdx.x * 256 + threadIdx.x;
    if (e < N_INC) {
        int h = hidx[e], n = nidx[e];
        int p = atomicAdd(&hcur[h], 1);
        hlist[hoff[h] + p] = n;
        int q = atomicAdd(&ncur[n], 1);
        nlist[noff[n] + q] = h;
    }
}

// ---------------- weight transpose+convert: W[K,512] f32 -> Wt[512,Kpad] bf16 ----------------
__global__ void wtrans_kernel(const float* __restrict__ W, short* __restrict__ Wt, int K, int Kpad) {
    int n = blockIdx.x;
    for (int k = threadIdx.x; k < Kpad; k += 64)
        Wt[(long)n * Kpad + k] = (k < K) ? f2bf(W[(long)k * D + n]) : (short)0;
}

// batched l2w transpose: 3 layers in one dispatch (grid 3*D)
__global__ void wtrans3_kernel(const float* __restrict__ W, short* __restrict__ Wt) {
    int layer = blockIdx.x >> 9;           // /512
    int n = blockIdx.x & 511;
    const float* src = W + (size_t)layer * D * D;
    short* dst = Wt + (size_t)layer * D * D;
    for (int k = threadIdx.x; k < D; k += 64)
        dst[(long)n * D + k] = f2bf(src[(long)k * D + n]);
}

// plain f32 -> bf16 convert (8/thread)
__global__ void cvt_f32_bf16_kernel(const float* __restrict__ src, short* __restrict__ dst) {
    long i = ((long)blockIdx.x * 256 + threadIdx.x) * 8;
    float4 f0 = *(const float4*)(src + i);
    float4 f1 = *(const float4*)(src + i + 4);
    short8 o;
    o[0] = f2bf(f0.x); o[1] = f2bf(f0.y); o[2] = f2bf(f0.z); o[3] = f2bf(f0.w);
    o[4] = f2bf(f1.x); o[5] = f2bf(f1.y); o[6] = f2bf(f1.z); o[7] = f2bf(f1.w);
    *(short8*)(dst + i) = o;
}

// W[rows,512] f32 -> dst[256,512] bf16, zero-padding rows >= rows_real
__global__ void cvt_w_pad_kernel(const float* __restrict__ src, short* __restrict__ dst, int rows_real) {
    int r = blockIdx.x;           // 0..255
    int c = threadIdx.x * 8;
    short8 o = (short8)0;
    if (r < rows_real) {
        float4 f0 = *(const float4*)(src + (long)r * D + c);
        float4 f1 = *(const float4*)(src + (long)r * D + c + 4);
        o[0] = f2bf(f0.x); o[1] = f2bf(f0.y); o[2] = f2bf(f0.z); o[3] = f2bf(f0.w);
        o[4] = f2bf(f1.x); o[5] = f2bf(f1.y); o[6] = f2bf(f1.z); o[7] = f2bf(f1.w);
    }
    *(short8*)(dst + (long)r * D + c) = o;
}

// vecmat: out[col] = sum_j v[j] * M[j*512+col]
__global__ __launch_bounds__(256) void vecmat_kernel(const float* __restrict__ v,
                                                     const float* __restrict__ M,
                                                     float* __restrict__ out) {
    int col = blockIdx.x * 256 + threadIdx.x;
    float a = 0.f;
    for (int j = 0; j < D; j++) a += v[j] * M[(long)j * D + col];
    out[col] = a;
}

__global__ void vecadd_kernel(const float* __restrict__ a, const float* __restrict__ b,
                              float* __restrict__ o) {
    int i = blockIdx.x * 256 + threadIdx.x;
    o[i] = a[i] + b[i];
}

// batched TB precompute: grid 6 (3 layers x 2 col-halves). TB[layer][4][512]
__global__ __launch_bounds__(256) void smallmm3_kernel(
    const float* __restrict__ temb, const float* __restrict__ l1b,
    const float* __restrict__ l2w, float* __restrict__ TB)
{
    int layer = blockIdx.x >> 1;
    int col = (blockIdx.x & 1) * 256 + threadIdx.x;
    const float* b1 = l1b + (size_t)layer * D;
    const float* W2 = l2w + (size_t)layer * D * D;
    float a0 = 0.f, a1 = 0.f, a2 = 0.f, a3 = 0.f;
    for (int j = 0; j < D; j++) {
        float w = W2[(long)j * D + col];
        a0 += temb[j] * w;
        a1 += temb[D + j] * w;
        a2 += temb[2 * D + j] * w;
        a3 += b1[j] * w;
    }
    float* o = TB + (size_t)layer * 4 * D;
    o[col] = a0; o[D + col] = a1; o[2 * D + col] = a2; o[3 * D + col] = a3;
}

// node_features [N,49] f32 -> A0 [NPAD,64] bf16 (zero pad)
__global__ void cvt_in_kernel(const float* __restrict__ nf, short* __restrict__ A0) {
    int r = blockIdx.x;
    int c = threadIdx.x;
    short v = 0;
    if (r < N_NODES && c < D_IN) v = f2bf(nf[(long)r * D_IN + c]);
    A0[(long)r * KPAD_IN + c] = v;
}

// hedge pre-sum, 512 cols (unrolled x2 gather): hs[e,:] = sum_{members} x[n,:]
__global__ __launch_bounds__(256) void hedge_sum_kernel(
    const short* __restrict__ x, const int* __restrict__ hoff, const int* __restrict__ hlist,
    short* __restrict__ hs)
{
    int row = blockIdx.x * 4 + (threadIdx.x >> 6);      // grid = HPAD/4
    int lane = threadIdx.x & 63;
    float acc[8] = {0, 0, 0, 0, 0, 0, 0, 0};
    if (row < N_HEDGES) {
        int s = hoff[row], e = hoff[row + 1];
        int j = s;
        for (; j + 1 < e; j += 2) {
            short8 v0 = *(const short8*)(x + (long)hlist[j] * D + lane * 8);
            short8 v1 = *(const short8*)(x + (long)hlist[j + 1] * D + lane * 8);
            #pragma unroll
            for (int k = 0; k < 8; k++) acc[k] += bf2f(v0[k]) + bf2f(v1[k]);
        }
        if (j < e) {
            short8 v0 = *(const short8*)(x + (long)hlist[j] * D + lane * 8);
            #pragma unroll
            for (int k = 0; k < 8; k++) acc[k] += bf2f(v0[k]);
        }
    }
    short8 o;
    #pragma unroll
    for (int k = 0; k < 8; k++) o[k] = f2bf(acc[k]);
    *(short8*)(hs + (long)row * D + lane * 8) = o;
}

// hedge pre-sum, 64 cols (layer-0 input features)
__global__ __launch_bounds__(256) void hedge_sum64_kernel(
    const short* __restrict__ A0, const int* __restrict__ hoff, const int* __restrict__ hlist,
    short* __restrict__ hs0)
{
    int row = blockIdx.x * 4 + (threadIdx.x >> 6);      // grid = HPAD/4
    int c = threadIdx.x & 63;
    float acc = 0.f;
    if (row < N_HEDGES) {
        int s = hoff[row], e = hoff[row + 1];
        int j = s;
        for (; j + 1 < e; j += 2) {
            float a = bf2f(A0[(long)hlist[j] * KPAD_IN + c]);
            float b = bf2f(A0[(long)hlist[j + 1] * KPAD_IN + c]);
            acc += a + b;
        }
        if (j < e) acc += bf2f(A0[(long)hlist[j] * KPAD_IN + c]);
    }
    hs0[(long)row * KPAD_IN + c] = f2bf(acc);
}

// fused node gather + residual + bias + LayerNorm + fast GELU.
// If outf == null: writes bf16 into x (in place). If outf != null: writes ONLY f32 outf.
__global__ __launch_bounds__(256) void node_ln_gelu_kernel(
    const short* __restrict__ hmsg, const int* __restrict__ noff, const int* __restrict__ nlist,
    short* __restrict__ x, const float* __restrict__ b2,
    const float* __restrict__ g, const float* __restrict__ b, float* __restrict__ outf)
{
    const int row = blockIdx.x * 4 + (threadIdx.x >> 6);
    const int lane = threadIdx.x & 63;
    int s = noff[row], e = noff[row + 1];
    float acc[8] = {0, 0, 0, 0, 0, 0, 0, 0};
    int j = s;
    for (; j + 1 < e; j += 2) {
        short8 v0 = *(const short8*)(hmsg + (long)nlist[j] * D + lane * 8);
        short8 v1 = *(const short8*)(hmsg + (long)nlist[j + 1] * D + lane * 8);
        #pragma unroll
        for (int k = 0; k < 8; k++) acc[k] += bf2f(v0[k]) + bf2f(v1[k]);
    }
    if (j < e) {
        short8 v0 = *(const short8*)(hmsg + (long)nlist[j] * D + lane * 8);
        #pragma unroll
        for (int k = 0; k < 8; k++) acc[k] += bf2f(v0[k]);
    }
    const float inv = 1.0f / fmaxf((float)(e - s), 1.0f);
    short8 xv = *(const short8*)(x + (long)row * D + lane * 8);
    const float4 c0 = *(const float4*)(b2 + lane * 8);
    const float4 c1 = *(const float4*)(b2 + lane * 8 + 4);
    const float cv[8] = {c0.x, c0.y, c0.z, c0.w, c1.x, c1.y, c1.z, c1.w};
    float f[8];
    float sum = 0.f, sq = 0.f;
    #pragma unroll
    for (int k = 0; k < 8; k++) {
        f[k] = acc[k] * inv + bf2f(xv[k]) + cv[k];
        sum += f[k]; sq += f[k] * f[k];
    }
    #pragma unroll
    for (int o = 32; o > 0; o >>= 1) { sum += __shfl_xor(sum, o, 64); sq += __shfl_xor(sq, o, 64); }
    const float mean = sum * (1.0f / D);
    const float var  = sq * (1.0f / D) - mean * mean;
    const float rstd = rsqrtf(var + 1e-5f);
    const float4 g0 = *(const float4*)(g + lane * 8);
    const float4 g1 = *(const float4*)(g + lane * 8 + 4);
    const float4 b0 = *(const float4*)(b + lane * 8);
    const float4 b1 = *(const float4*)(b + lane * 8 + 4);
    const float gv[8] = {g0.x, g0.y, g0.z, g0.w, g1.x, g1.y, g1.z, g1.w};
    const float bv[8] = {b0.x, b0.y, b0.z, b0.w, b1.x, b1.y, b1.z, b1.w};
    float yout[8];
    #pragma unroll
    for (int k = 0; k < 8; k++) {
        float y = (f[k] - mean) * rstd * gv[k] + bv[k];
        yout[k] = fast_gelu(y);
    }
    if (outf) {
        float4 o0 = {yout[0], yout[1], yout[2], yout[3]};
        float4 o1 = {yout[4], yout[5], yout[6], yout[7]};
        *(float4*)(outf + (long)row * D + lane * 8) = o0;
        *(float4*)(outf + (long)row * D + lane * 8 + 4) = o1;
    } else {
        short8 o8;
        #pragma unroll
        for (int k = 0; k < 8; k++) o8[k] = f2bf(yout[k]);
        *(short8*)(x + (long)row * D + lane * 8) = o8;
    }
}

// graph pooling via sorted batch segments (f32 in, bf16 out)
__global__ __launch_bounds__(64) void pool_kernel(const float* __restrict__ x, const int* __restrict__ batch,
                                                  short* __restrict__ Gbf) {
    int g = blockIdx.x;
    int lo = 0, hi = N_NODES;
    while (lo < hi) { int mid = (lo + hi) >> 1; if (batch[mid] < g) lo = mid + 1; else hi = mid; }
    int s = lo;
    hi = N_NODES;
    while (lo < hi) { int mid = (lo + hi) >> 1; if (batch[mid] < g + 1) lo = mid + 1; else hi = mid; }
    int e = lo;
    int lane = threadIdx.x;
    float acc[8] = {0, 0, 0, 0, 0, 0, 0, 0};
    for (int r = s; r < e; r++) {
        const float* rp = x + (long)r * D + lane * 8;
        float4 v0 = *(const float4*)rp;
        float4 v1 = *(const float4*)(rp + 4);
        acc[0] += v0.x; acc[1] += v0.y; acc[2] += v0.z; acc[3] += v0.w;
        acc[4] += v1.x; acc[5] += v1.y; acc[6] += v1.z; acc[7] += v1.w;
    }
    float inv = 1.0f / fmaxf((float)(e - s), 1.0f);
    short8 o;
    #pragma unroll
    for (int k = 0; k < 8; k++) o[k] = f2bf(acc[k] * inv);
    *(short8*)(Gbf + (long)g * D + lane * 8) = o;
}

__global__ void batchf_kernel(const int* __restrict__ batch, float* __restrict__ ob) {
    int i = blockIdx.x * 256 + threadIdx.x;
    if (i < N_NODES) ob[i] = (float)batch[i];
}

extern "C" void kernel_launch(void* const* d_in, const int* in_sizes, int n_in,
                              void* d_out, int out_size, void* d_ws, size_t ws_size,
                              hipStream_t stream) {
    (void)in_sizes; (void)n_in; (void)out_size; (void)ws_size;
    const float* nf    = (const float*)d_in[0];
    const int*   nidx  = (const int*)d_in[1];
    const int*   hidx  = (const int*)d_in[2];
    const int*   htype = (const int*)d_in[3];
    const int*   batch = (const int*)d_in[4];
    const float* in_w  = (const float*)d_in[6];
    const float* in_b  = (const float*)d_in[7];
    const float* temb  = (const float*)d_in[8];
    const float* l1w   = (const float*)d_in[9];
    const float* l1b   = (const float*)d_in[10];
    const float* l2w   = (const float*)d_in[11];
    const float* l2b   = (const float*)d_in[12];
    const float* lng   = (const float*)d_in[13];
    const float* lnb   = (const float*)d_in[14];
    const float* outw  = (const float*)d_in[15];
    const float* outb  = (const float*)d_in[16];

    float* out_graph = (float*)d_out;                       // [1024,512]
    float* out_nodes = out_graph + (long)N_GRAPHS * D;      // [100000,512]
    float* out_batch = out_nodes + (long)N_NODES * D;       // [100000]

    char* wsb = (char*)d_ws;
    size_t off = 0;
    auto alloc = [&](size_t bytes) {
        void* p = wsb + off;
        off += (bytes + 255) & ~(size_t)255;
        return p;
    };
    short* x_bf  = (short*)alloc((size_t)NPAD * D * 2);
    short* hs_bf = (short*)alloc((size_t)HPAD * D * 2);
    short* h_bf  = (short*)alloc((size_t)HPAD * D * 2);
    short* hs0   = (short*)alloc((size_t)HPAD * KPAD_IN * 2);
    short* G_bf  = (short*)alloc((size_t)N_GRAPHS * D * 2);
    short* A0    = (short*)alloc((size_t)NPAD * KPAD_IN * 2);
    short* wt    = (short*)alloc((size_t)D * D * 2);
    short* wt3   = (short*)alloc((size_t)3 * D * D * 2);
    short* w1bf  = (short*)alloc((size_t)3 * D * D * 2);
    short* W12t  = (short*)alloc((size_t)3 * D * D * 2);
    short* inwbf = (short*)alloc((size_t)256 * D * 2);
    short* M0t   = (short*)alloc((size_t)D * KPAD_IN * 2);
    float* TB    = (float*)alloc((size_t)3 * 4 * D * 4);
    float* tmpv  = (float*)alloc((size_t)D * 4);
    float* bias0 = (float*)alloc((size_t)D * 4);
    float* bb0   = (float*)alloc((size_t)D * 4);
    int* cnt_h   = (int*)alloc((size_t)HPAD * 4);
    int* cnt_n   = (int*)alloc((size_t)N_NODES * 4);
    int* hoff    = (int*)alloc((size_t)(N_HEDGES + 1) * 4);
    int* noff    = (int*)alloc((size_t)(N_NODES + 1) * 4);
    int* hcur    = (int*)alloc((size_t)N_HEDGES * 4);
    int* ncur    = (int*)alloc((size_t)N_NODES * 4);
    int* hlist   = (int*)alloc((size_t)N_INC * 4);
    int* nlist   = (int*)alloc((size_t)N_INC * 4);
    int* bsum    = (int*)alloc((size_t)256 * 4);

    // ---- build CSR (both directions) ----
    hipMemsetAsync(cnt_h, 0, (size_t)HPAD * 4, stream);
    hipMemsetAsync(cnt_n, 0, (size_t)N_NODES * 4, stream);
    hipMemsetAsync(hcur,  0, (size_t)N_HEDGES * 4, stream);
    hipMemsetAsync(ncur,  0, (size_t)N_NODES * 4, stream);
    count_inc_kernel<<<(N_INC + 255) / 256, 256, 0, stream>>>(nidx, hidx, cnt_n, cnt_h);
    const int NBH = (N_HEDGES + 2047) / 2048;
    const int NBN = (N_NODES + 2047) / 2048;
    scan1_kernel<<<NBH, 256, 0, stream>>>(cnt_h, hoff, bsum, N_HEDGES);
    scan2_kernel<<<1, 256, 0, stream>>>(bsum, NBH, hoff + N_HEDGES);
    scan3_kernel<<<NBH, 256, 0, stream>>>(hoff, bsum, N_HEDGES);
    scan1_kernel<<<NBN, 256, 0, stream>>>(cnt_n, noff, bsum, N_NODES);
    scan2_kernel<<<1, 256, 0, stream>>>(bsum, NBN, noff + N_NODES);
    scan3_kernel<<<NBN, 256, 0, stream>>>(noff, bsum, N_NODES);
    place_kernel<<<(N_INC + 255) / 256, 256, 0, stream>>>(nidx, hidx, hoff, noff, hcur, ncur, hlist, nlist);
    batchf_kernel<<<(N_NODES + 255) / 256, 256, 0, stream>>>(batch, out_batch);

    // ---- weight precompute (batched): W12t[i] = (l1_w[i] @ l2_w[i])^T ; TB[i] ----
    cvt_f32_bf16_kernel<<<(3 * D * D / 8) / 256, 256, 0, stream>>>(l1w, w1bf);
    wtrans3_kernel<<<3 * D, 64, 0, stream>>>(l2w, wt3);
    gemm_bf16<<<24, 512, 0, stream>>>(w1bf, wt3, nullptr, nullptr, nullptr, W12t, D,
                                      nullptr, nullptr, nullptr, nullptr, D, 4,
                                      8, (long)D * D, (long)D * D, (long)D * D);
    smallmm3_kernel<<<6, 256, 0, stream>>>(temb, l1b, l2w, TB);

    // ---- layer-0 shortcut: M0t = (in_w @ W12[0])^T (K=64-packed); bb0 = bias0 + b1W2_0 ----
    cvt_w_pad_kernel<<<256, 64, 0, stream>>>(in_w, inwbf, D_IN);
    gemm_bf16<<<4, 512, 0, stream>>>(inwbf, W12t, nullptr, nullptr, nullptr, M0t, KPAD_IN,
                                     nullptr, nullptr, nullptr, nullptr, D, 4, 0, 0, 0, 0);
    vecmat_kernel<<<2, 256, 0, stream>>>(in_b, l1w, tmpv);
    vecmat_kernel<<<2, 256, 0, stream>>>(tmpv, l2w, bias0);
    vecadd_kernel<<<2, 256, 0, stream>>>(bias0, TB + 3 * D, bb0);

    // ---- input projection: x_bf = bf16(nf @ in_w + in_b) ----
    wtrans_kernel<<<D, 64, 0, stream>>>(in_w, wt, D_IN, KPAD_IN);
    cvt_in_kernel<<<NPAD, 64, 0, stream>>>(nf, A0);
    const int NWG  = (NPAD / 256) * 4;   // 1564
    const int NWGH = (HPAD / 256) * 4;   // 784
    gemm_bf16<<<NWG, 512, 0, stream>>>(A0, wt, in_b, x_bf, nullptr, nullptr, 0,
                                       nullptr, nullptr, nullptr, nullptr, KPAD_IN, 4, 0, 0, 0, 0);

    for (int i = 0; i < 3; i++) {
        // hedge pre-sum (Ah·x), then hedge-space GEMM with fused message epilogue
        if (i == 0) {
            hedge_sum64_kernel<<<HPAD / 4, 256, 0, stream>>>(A0, hoff, hlist, hs0);
            gemm_bf16<<<NWGH, 512, 0, stream>>>(hs0, M0t, nullptr, h_bf, nullptr, nullptr, 0,
                                                cnt_h, htype, TB, bb0, KPAD_IN, 4, 0, 0, 0, 0);
        } else {
            hedge_sum_kernel<<<HPAD / 4, 256, 0, stream>>>(x_bf, hoff, hlist, hs_bf);
            gemm_bf16<<<NWGH, 512, 0, stream>>>(hs_bf, W12t + (size_t)i * D * D, nullptr,
                                                h_bf, nullptr, nullptr, 0,
                                                cnt_h, htype, TB + (size_t)i * 4 * D,
                                                TB + (size_t)i * 4 * D + 3 * D, D, 4, 0, 0, 0, 0);
        }
        // x = fast_gelu(LN(segsum(h)/clip + x + b2)); last layer writes ONLY f32 out_nodes
        node_ln_gelu_kernel<<<N_NODES / 4, 256, 0, stream>>>(h_bf, noff, nlist, x_bf,
                                                             l2b + (size_t)i * D,
                                                             lng + (size_t)i * D, lnb + (size_t)i * D,
                                                             (i < 2) ? nullptr : out_nodes);
    }

    // ---- graph pooling (reads f32 out_nodes) + output projection ----
    pool_kernel<<<N_GRAPHS, 64, 0, stream>>>(out_nodes, batch, G_bf);
    wtrans_kernel<<<D, 64, 0, stream>>>(outw, wt, D, D);
    gemm_bf16<<<(N_GRAPHS / 256) * 4, 512, 0, stream>>>(G_bf, wt, outb, nullptr, out_graph, nullptr, 0,
                                                        nullptr, nullptr, nullptr, nullptr, D, 4, 0, 0, 0, 0);
}

// Round 16
// 849.202 us; speedup vs baseline: 1.0599x; 1.0445x over previous
//
#include <hip/hip_runtime.h>
#include <math.h>

#define N_NODES  100000
#define N_HEDGES 50000
#define HPAD     50176    // 196 * 256
#define N_INC    300000
#define N_GRAPHS 1024
#define D_IN     49
#define D        512
#define NPAD     100096   // 391 * 256
#define KPAD_IN  64

typedef __attribute__((ext_vector_type(8))) short short8;
typedef __attribute__((ext_vector_type(8))) __bf16 bf16x8;
typedef __attribute__((ext_vector_type(4))) float f32x4;

__device__ __forceinline__ short f2bf(float f) {
    union { float f; unsigned u; } v; v.f = f;
    unsigned r = v.u + 0x7fffu + ((v.u >> 16) & 1u);
    return (short)(r >> 16);
}
__device__ __forceinline__ float bf2f(short s) {
    union { unsigned u; float f; } v; v.u = ((unsigned)(unsigned short)s) << 16;
    return v.f;
}

// fast tanh-form GELU (|err| <= ~1e-3 abs; threshold 20.48)
__device__ __forceinline__ float fast_gelu(float y) {
    const float y2 = y * y;
    const float p  = fmaf(y2, 0.0356774081f, 0.7978845608f);
    float arg = y * p * 2.8853900818f;
    arg = fminf(fmaxf(arg, -30.0f), 30.0f);
    const float u = __builtin_exp2f(arg);
    return y * u * __builtin_amdgcn_rcpf(1.0f + u);
}

__device__ __forceinline__ void gld16(const void* g, void* l) {
    __builtin_amdgcn_global_load_lds(
        (const __attribute__((address_space(1))) unsigned int*)g,
        (__attribute__((address_space(3))) unsigned int*)l, 16, 0, 0);
}

// ---------------- GEMM: C[M,512] = A[M,K](bf16) @ Bt[512,K](bf16), flexible epilogues --------------
// 256x128 tile, 8 waves. global_load_lds(16B) staging, pre-swizzled source. 2-buffer + counted
// vmcnt(3). 48KB LDS -> 3 blocks/CU. Builtin MFMA.
// Hedge mode (hoffp != null): cnt = hoffp[row+1]-hoffp[row]; v=(acc+cnt*bb)/clip(cnt)+tembW2[type].
__global__ __launch_bounds__(512) void gemm_bf16(
    const short* __restrict__ A, const short* __restrict__ Bt,
    const float* __restrict__ bias,
    short* __restrict__ Cbf, float* __restrict__ Cf, short* __restrict__ CbfT, int strideT,
    const int* __restrict__ hoffp, const int* __restrict__ htypes,
    const float* __restrict__ tembW2, const float* __restrict__ bb,
    int K, int nby, int layerWGs, long aStr, long bStr, long cStr)
{
    __shared__ short lds[24576];          // As: 2x256x32 @0 ; Bs: 2x128x32 @16384 ; epilogue overlay @0
    const int tid  = threadIdx.x;
    const int lane = tid & 63;
    const int wave = tid >> 6;
    const int wr = wave >> 1;
    const int wc = wave & 1;

    // bijective XCD-aware swizzle (m204)
    const int nwg = gridDim.x;
    const int q8 = nwg >> 3, r8 = nwg & 7;
    const int xcd = blockIdx.x & 7, loc = blockIdx.x >> 3;
    int wg = (xcd < r8) ? (xcd * (q8 + 1) + loc) : (r8 * (q8 + 1) + (xcd - r8) * q8 + loc);
    if (layerWGs) {
        const int layer = wg / layerWGs;
        wg %= layerWGs;
        A += layer * aStr;
        Bt += layer * bStr;
        if (CbfT) CbfT += layer * cStr;
    }
    const long row0 = (long)(wg / nby) * 256;
    const int  col0 = (wg % nby) * 128;

    f32x4 acc[4][4];
    #pragma unroll
    for (int m = 0; m < 4; m++)
        #pragma unroll
        for (int n = 0; n < 4; n++)
            acc[m][n] = (f32x4)(0.0f);

    const int ch   = lane & 3;
    const int rofs = lane >> 2;
    const short* aSrc[2];
    const short* bSrc;
    #pragma unroll
    for (int j = 0; j < 2; j++) {
        const int rloc = (wave * 2 + j) * 16 + rofs;
        const int sw = (rloc >> 1) & 3;
        aSrc[j] = A + (row0 + rloc) * (long)K + (ch ^ sw) * 8;
    }
    {
        const int rlb = wave * 16 + rofs;
        const int swb = (rlb >> 1) & 3;
        bSrc = Bt + ((long)col0 + rlb) * K + (ch ^ swb) * 8;
    }

    const int ks = lane >> 4;
    const int rl = lane & 15;
    const int nk = K >> 5;

    gld16(aSrc[0], &lds[(wave * 2) * 16 * 32]);
    gld16(aSrc[1], &lds[(wave * 2 + 1) * 16 * 32]);
    gld16(bSrc,    &lds[16384 + wave * 16 * 32]);
    if (nk > 1) {
        gld16(aSrc[0] + 32, &lds[8192 + (wave * 2) * 16 * 32]);
        gld16(aSrc[1] + 32, &lds[8192 + (wave * 2 + 1) * 16 * 32]);
        gld16(bSrc    + 32, &lds[16384 + 4096 + wave * 16 * 32]);
    }

    for (int t = 0; t < nk; t++) {
        if (t + 1 < nk) asm volatile("s_waitcnt vmcnt(3)" ::: "memory");
        else            asm volatile("s_waitcnt vmcnt(0)" ::: "memory");
        __builtin_amdgcn_s_barrier();
        __builtin_amdgcn_sched_barrier(0);
        const int cb = t & 1;
        bf16x8 a[4], b[4];
        #pragma unroll
        for (int m = 0; m < 4; m++) {
            const int rr = wr * 64 + m * 16 + rl;
            a[m] = *(const bf16x8*)&lds[cb * 8192 + rr * 32 + (ks ^ ((rr >> 1) & 3)) * 8];
        }
        #pragma unroll
        for (int n = 0; n < 4; n++) {
            const int rr = wc * 64 + n * 16 + rl;
            b[n] = *(const bf16x8*)&lds[16384 + cb * 4096 + rr * 32 + (ks ^ ((rr >> 1) & 3)) * 8];
        }
        #pragma unroll
        for (int m = 0; m < 4; m++)
            #pragma unroll
            for (int n = 0; n < 4; n++)
                acc[m][n] = __builtin_amdgcn_mfma_f32_16x16x32_bf16(a[m], b[n], acc[m][n], 0, 0, 0);
        __builtin_amdgcn_sched_barrier(0);
        __builtin_amdgcn_s_barrier();
        if (t + 2 < nk) {
            gld16(aSrc[0] + (t + 2) * 32, &lds[cb * 8192 + (wave * 2) * 16 * 32]);
            gld16(aSrc[1] + (t + 2) * 32, &lds[cb * 8192 + (wave * 2 + 1) * 16 * 32]);
            gld16(bSrc    + (t + 2) * 32, &lds[16384 + cb * 4096 + wave * 16 * 32]);
        }
    }

    const int rl2 = lane & 15;
    if (Cbf && !Cf && !CbfT) {
        float bbv[4], tw0[4], tw1[4], tw2[4], biv[4];
        #pragma unroll
        for (int n = 0; n < 4; n++) {
            const int col = col0 + wc * 64 + n * 16 + rl2;
            if (hoffp) {
                bbv[n] = bb[col];
                tw0[n] = tembW2[col];
                tw1[n] = tembW2[D + col];
                tw2[n] = tembW2[2 * D + col];
            } else {
                biv[n] = bias ? bias[col] : 0.0f;
            }
        }
        short* ep = &lds[wave * 2304];
        #pragma unroll
        for (int p = 0; p < 2; p++) {
            #pragma unroll
            for (int mm = 0; mm < 2; mm++) {
                const int m = 2 * p + mm;
                #pragma unroll
                for (int rr = 0; rr < 4; rr++) {
                    const long row = row0 + wr * 64 + m * 16 + (lane >> 4) * 4 + rr;
                    const int  lr  = mm * 16 + (lane >> 4) * 4 + rr;
                    if (hoffp) {
                        const bool valid = row < N_HEDGES;
                        const float cf  = valid ? (float)(hoffp[row + 1] - hoffp[row]) : 0.0f;
                        const float icf = 1.0f / fmaxf(cf, 1.0f);
                        const int ty = valid ? htypes[row] : 0;
                        #pragma unroll
                        for (int n = 0; n < 4; n++) {
                            float tsel = (ty == 0) ? tw0[n] : (ty == 1) ? tw1[n] : tw2[n];
                            float v = (acc[m][n][rr] + cf * bbv[n]) * icf + tsel;
                            ep[lr * 72 + n * 16 + rl2] = f2bf(v);
                        }
                    } else {
                        #pragma unroll
                        for (int n = 0; n < 4; n++) {
                            float v = acc[m][n][rr] + biv[n];
                            ep[lr * 72 + n * 16 + rl2] = f2bf(v);
                        }
                    }
                }
            }
            __syncthreads();
            #pragma unroll
            for (int i = 0; i < 4; i++) {
                const int lr2 = i * 8 + (lane >> 3);
                const int c2  = lane & 7;
                short8 vv = *(const short8*)&ep[lr2 * 72 + c2 * 8];
                const long row = row0 + wr * 64 + p * 32 + lr2;
                *(short8*)&Cbf[row * D + col0 + wc * 64 + c2 * 8] = vv;
            }
            __syncthreads();
        }
    } else {
        const int rb4 = wr * 64 + (lane >> 4) * 4;
        #pragma unroll
        for (int m = 0; m < 4; m++) {
            #pragma unroll
            for (int n = 0; n < 4; n++) {
                const int col = col0 + wc * 64 + n * 16 + rl2;
                const float bi = bias ? bias[col] : 0.0f;
                #pragma unroll
                for (int rr = 0; rr < 4; rr++) {
                    const long row = row0 + rb4 + m * 16 + rr;
                    float v = acc[m][n][rr];
                    if (hoffp) {
                        const bool valid = row < N_HEDGES;
                        const float cf = valid ? (float)(hoffp[row + 1] - hoffp[row]) : 0.0f;
                        const int ty = valid ? htypes[row] : 0;
                        v = (v + cf * bb[col]) * (1.0f / fmaxf(cf, 1.0f)) + tembW2[(long)ty * D + col];
                    } else {
                        v += bi;
                    }
                    if (Cbf)  Cbf[row * D + col] = f2bf(v);
                    if (Cf)   Cf[row * D + col]  = v;
                    if (CbfT && row < strideT) CbfT[(long)col * strideT + row] = f2bf(v);
                }
            }
        }
    }
}

// ---------------- degree counts + batch float output (fused) ----------------
__global__ void count_inc_kernel(const int* __restrict__ nidx, const int* __restrict__ hidx,
                                 const int* __restrict__ batch, int* cnt_n, int* cnt_h,
                                 float* __restrict__ ob) {
    int i = blockIdx.x * 256 + threadIdx.x;
    if (i < N_INC) {
        atomicAdd(&cnt_h[hidx[i]], 1);
        atomicAdd(&cnt_n[nidx[i]], 1);
    }
    if (i < N_NODES) ob[i] = (float)batch[i];
}

// ---------------- hierarchical exclusive scan (3 phases, 2048 elems/block) ----------------
__global__ __launch_bounds__(256) void scan1_kernel(const int* __restrict__ cnt, int* __restrict__ out,
                                                    int* __restrict__ bsum, int n) {
    __shared__ int s[256];
    const int t = threadIdx.x;
    const long base = (long)blockIdx.x * 2048 + t * 8;
    int v[8];
    int ts = 0;
    #pragma unroll
    for (int j = 0; j < 8; j++) {
        v[j] = (base + j < n) ? cnt[base + j] : 0;
        ts += v[j];
    }
    s[t] = ts;
    __syncthreads();
    for (int ofs = 1; ofs < 256; ofs <<= 1) {
        int x = (t >= ofs) ? s[t - ofs] : 0;
        __syncthreads();
        s[t] += x;
        __syncthreads();
    }
    int run = (t == 0) ? 0 : s[t - 1];
    #pragma unroll
    for (int j = 0; j < 8; j++) {
        if (base + j < n) out[base + j] = run;
        run += v[j];
    }
    if (t == 255) bsum[blockIdx.x] = s[255];
}

// scan both block-sum arrays in one dispatch: block 0 -> (bsumA,nA,totalA), block 1 -> (bsumB,nB,totalB)
__global__ __launch_bounds__(256) void scan2both_kernel(int* __restrict__ bsumA, int nA, int* __restrict__ totalA,
                                                        int* __restrict__ bsumB, int nB, int* __restrict__ totalB) {
    int* bsum = blockIdx.x ? bsumB : bsumA;
    int  nb   = blockIdx.x ? nB : nA;
    int* total = blockIdx.x ? totalB : totalA;
    __shared__ int s[256];
    const int t = threadIdx.x;
    int v = (t < nb) ? bsum[t] : 0;
    s[t] = v;
    __syncthreads();
    for (int ofs = 1; ofs < 256; ofs <<= 1) {
        int x = (t >= ofs) ? s[t - ofs] : 0;
        __syncthreads();
        s[t] += x;
        __syncthreads();
    }
    if (t < nb) bsum[t] = (t == 0) ? 0 : s[t - 1];
    if (t == 255) *total = s[255];
}

__global__ __launch_bounds__(256) void scan3_kernel(int* __restrict__ out, const int* __restrict__ bsum, int n) {
    const int add = bsum[blockIdx.x];
    if (add == 0) return;
    const long base = (long)blockIdx.x * 2048 + threadIdx.x * 8;
    #pragma unroll
    for (int j = 0; j < 8; j++)
        if (base + j < n) out[base + j] += add;
}

// CSR placement; consumes cnt arrays as cursors via atomicSub (counts not needed afterwards)
__global__ void place_kernel(const int* __restrict__ nidx, const int* __restrict__ hidx,
                             const int* __restrict__ hoff, const int* __restrict__ noff,
                             int* cnt_h, int* cnt_n, int* __restrict__ hlist, int* __restrict__ nlist) {
    int e = blockIdx.x * 256 + threadIdx.x;
    if (e < N_INC) {
        int h = hidx[e], n = nidx[e];
        int p = atomicSub(&cnt_h[h], 1) - 1;
        hlist[hoff[h] + p] = n;
        int q = atomicSub(&cnt_n[n], 1) - 1;
        nlist[noff[n] + q] = h;
    }
}

// ---------------- weight transpose+convert: W[K,512] f32 -> Wt[512,Kpad] bf16 ----------------
__global__ void wtrans_kernel(const float* __restrict__ W, short* __restrict__ Wt, int K, int Kpad) {
    int n = blockIdx.x;
    for (int k = threadIdx.x; k < Kpad; k += 64)
        Wt[(long)n * Kpad + k] = (k < K) ? f2bf(W[(long)k * D + n]) : (short)0;
}

// batched l2w transpose: 3 layers in one dispatch (grid 3*D)
__global__ void wtrans3_kernel(const float* __restrict__ W, short* __restrict__ Wt) {
    int layer = blockIdx.x >> 9;
    int n = blockIdx.x & 511;
    const float* src = W + (size_t)layer * D * D;
    short* dst = Wt + (size_t)layer * D * D;
    for (int k = threadIdx.x; k < D; k += 64)
        dst[(long)n * D + k] = f2bf(src[(long)k * D + n]);
}

// plain f32 -> bf16 convert (8/thread)
__global__ void cvt_f32_bf16_kernel(const float* __restrict__ src, short* __restrict__ dst) {
    long i = ((long)blockIdx.x * 256 + threadIdx.x) * 8;
    float4 f0 = *(const float4*)(src + i);
    float4 f1 = *(const float4*)(src + i + 4);
    short8 o;
    o[0] = f2bf(f0.x); o[1] = f2bf(f0.y); o[2] = f2bf(f0.z); o[3] = f2bf(f0.w);
    o[4] = f2bf(f1.x); o[5] = f2bf(f1.y); o[6] = f2bf(f1.z); o[7] = f2bf(f1.w);
    *(short8*)(dst + i) = o;
}

// W[rows,512] f32 -> dst[256,512] bf16, zero-padding rows >= rows_real
__global__ void cvt_w_pad_kernel(const float* __restrict__ src, short* __restrict__ dst, int rows_real) {
    int r = blockIdx.x;
    int c = threadIdx.x * 8;
    short8 o = (short8)0;
    if (r < rows_real) {
        float4 f0 = *(const float4*)(src + (long)r * D + c);
        float4 f1 = *(const float4*)(src + (long)r * D + c + 4);
        o[0] = f2bf(f0.x); o[1] = f2bf(f0.y); o[2] = f2bf(f0.z); o[3] = f2bf(f0.w);
        o[4] = f2bf(f1.x); o[5] = f2bf(f1.y); o[6] = f2bf(f1.z); o[7] = f2bf(f1.w);
    }
    *(short8*)(dst + (long)r * D + c) = o;
}

// vecmat: out[col] = sum_j v[j] * M[j*512+col]
__global__ __launch_bounds__(256) void vecmat_kernel(const float* __restrict__ v,
                                                     const float* __restrict__ M,
                                                     float* __restrict__ out) {
    int col = blockIdx.x * 256 + threadIdx.x;
    float a = 0.f;
    for (int j = 0; j < D; j++) a += v[j] * M[(long)j * D + col];
    out[col] = a;
}

// vecmat + add: out[col] = sum_j v[j]*M[j][col] + add[col]
__global__ __launch_bounds__(256) void vecmat_add_kernel(const float* __restrict__ v,
                                                         const float* __restrict__ M,
                                                         const float* __restrict__ addv,
                                                         float* __restrict__ out) {
    int col = blockIdx.x * 256 + threadIdx.x;
    float a = addv[col];
    for (int j = 0; j < D; j++) a += v[j] * M[(long)j * D + col];
    out[col] = a;
}

// batched TB precompute: grid 6 (3 layers x 2 col-halves). TB[layer][4][512]
__global__ __launch_bounds__(256) void smallmm3_kernel(
    const float* __restrict__ temb, const float* __restrict__ l1b,
    const float* __restrict__ l2w, float* __restrict__ TB)
{
    int layer = blockIdx.x >> 1;
    int col = (blockIdx.x & 1) * 256 + threadIdx.x;
    const float* b1 = l1b + (size_t)layer * D;
    const float* W2 = l2w + (size_t)layer * D * D;
    float a0 = 0.f, a1 = 0.f, a2 = 0.f, a3 = 0.f;
    for (int j = 0; j < D; j++) {
        float w = W2[(long)j * D + col];
        a0 += temb[j] * w;
        a1 += temb[D + j] * w;
        a2 += temb[2 * D + j] * w;
        a3 += b1[j] * w;
    }
    float* o = TB + (size_t)layer * 4 * D;
    o[col] = a0; o[D + col] = a1; o[2 * D + col] = a2; o[3 * D + col] = a3;
}

// node_features [N,49] f32 -> A0 [NPAD,64] bf16 (zero pad)
__global__ void cvt_in_kernel(const float* __restrict__ nf, short* __restrict__ A0) {
    int r = blockIdx.x;
    int c = threadIdx.x;
    short v = 0;
    if (r < N_NODES && c < D_IN) v = f2bf(nf[(long)r * D_IN + c]);
    A0[(long)r * KPAD_IN + c] = v;
}

// hedge pre-sum, 512 cols (unrolled x2 gather): hs[e,:] = sum_{members} x[n,:]
__global__ __launch_bounds__(256) void hedge_sum_kernel(
    const short* __restrict__ x, const int* __restrict__ hoff, const int* __restrict__ hlist,
    short* __restrict__ hs)
{
    int row = blockIdx.x * 4 + (threadIdx.x >> 6);
    int lane = threadIdx.x & 63;
    float acc[8] = {0, 0, 0, 0, 0, 0, 0, 0};
    if (row < N_HEDGES) {
        int s = hoff[row], e = hoff[row + 1];
        int j = s;
        for (; j + 1 < e; j += 2) {
            short8 v0 = *(const short8*)(x + (long)hlist[j] * D + lane * 8);
            short8 v1 = *(const short8*)(x + (long)hlist[j + 1] * D + lane * 8);
            #pragma unroll
            for (int k = 0; k < 8; k++) acc[k] += bf2f(v0[k]) + bf2f(v1[k]);
        }
        if (j < e) {
            short8 v0 = *(const short8*)(x + (long)hlist[j] * D + lane * 8);
            #pragma unroll
            for (int k = 0; k < 8; k++) acc[k] += bf2f(v0[k]);
        }
    }
    short8 o;
    #pragma unroll
    for (int k = 0; k < 8; k++) o[k] = f2bf(acc[k]);
    *(short8*)(hs + (long)row * D + lane * 8) = o;
}

// hedge pre-sum, 64 cols (layer-0 input features)
__global__ __launch_bounds__(256) void hedge_sum64_kernel(
    const short* __restrict__ A0, const int* __restrict__ hoff, const int* __restrict__ hlist,
    short* __restrict__ hs0)
{
    int row = blockIdx.x * 4 + (threadIdx.x >> 6);
    int c = threadIdx.x & 63;
    float acc = 0.f;
    if (row < N_HEDGES) {
        int s = hoff[row], e = hoff[row + 1];
        int j = s;
        for (; j + 1 < e; j += 2) {
            float a = bf2f(A0[(long)hlist[j] * KPAD_IN + c]);
            float b = bf2f(A0[(long)hlist[j + 1] * KPAD_IN + c]);
            acc += a + b;
        }
        if (j < e) acc += bf2f(A0[(long)hlist[j] * KPAD_IN + c]);
    }
    hs0[(long)row * KPAD_IN + c] = f2bf(acc);
}

// fused node gather + residual + bias + LayerNorm + fast GELU.
__global__ __launch_bounds__(256) void node_ln_gelu_kernel(
    const short* __restrict__ hmsg, const int* __restrict__ noff, const int* __restrict__ nlist,
    short* __restrict__ x, const float* __restrict__ b2,
    const float* __restrict__ g, const float* __restrict__ b, float* __restrict__ outf)
{
    const int row = blockIdx.x * 4 + (threadIdx.x >> 6);
    const int lane = threadIdx.x & 63;
    int s = noff[row], e = noff[row + 1];
    float acc[8] = {0, 0, 0, 0, 0, 0, 0, 0};
    int j = s;
    for (; j + 1 < e; j += 2) {
        short8 v0 = *(const short8*)(hmsg + (long)nlist[j] * D + lane * 8);
        short8 v1 = *(const short8*)(hmsg + (long)nlist[j + 1] * D + lane * 8);
        #pragma unroll
        for (int k = 0; k < 8; k++) acc[k] += bf2f(v0[k]) + bf2f(v1[k]);
    }
    if (j < e) {
        short8 v0 = *(const short8*)(hmsg + (long)nlist[j] * D + lane * 8);
        #pragma unroll
        for (int k = 0; k < 8; k++) acc[k] += bf2f(v0[k]);
    }
    const float inv = 1.0f / fmaxf((float)(e - s), 1.0f);
    short8 xv = *(const short8*)(x + (long)row * D + lane * 8);
    const float4 c0 = *(const float4*)(b2 + lane * 8);
    const float4 c1 = *(const float4*)(b2 + lane * 8 + 4);
    const float cv[8] = {c0.x, c0.y, c0.z, c0.w, c1.x, c1.y, c1.z, c1.w};
    float f[8];
    float sum = 0.f, sq = 0.f;
    #pragma unroll
    for (int k = 0; k < 8; k++) {
        f[k] = acc[k] * inv + bf2f(xv[k]) + cv[k];
        sum += f[k]; sq += f[k] * f[k];
    }
    #pragma unroll
    for (int o = 32; o > 0; o >>= 1) { sum += __shfl_xor(sum, o, 64); sq += __shfl_xor(sq, o, 64); }
    const float mean = sum * (1.0f / D);
    const float var  = sq * (1.0f / D) - mean * mean;
    const float rstd = rsqrtf(var + 1e-5f);
    const float4 g0 = *(const float4*)(g + lane * 8);
    const float4 g1 = *(const float4*)(g + lane * 8 + 4);
    const float4 b0 = *(const float4*)(b + lane * 8);
    const float4 b1 = *(const float4*)(b + lane * 8 + 4);
    const float gv[8] = {g0.x, g0.y, g0.z, g0.w, g1.x, g1.y, g1.z, g1.w};
    const float bv[8] = {b0.x, b0.y, b0.z, b0.w, b1.x, b1.y, b1.z, b1.w};
    float yout[8];
    #pragma unroll
    for (int k = 0; k < 8; k++) {
        float y = (f[k] - mean) * rstd * gv[k] + bv[k];
        yout[k] = fast_gelu(y);
    }
    if (outf) {
        float4 o0 = {yout[0], yout[1], yout[2], yout[3]};
        float4 o1 = {yout[4], yout[5], yout[6], yout[7]};
        *(float4*)(outf + (long)row * D + lane * 8) = o0;
        *(float4*)(outf + (long)row * D + lane * 8 + 4) = o1;
    } else {
        short8 o8;
        #pragma unroll
        for (int k = 0; k < 8; k++) o8[k] = f2bf(yout[k]);
        *(short8*)(x + (long)row * D + lane * 8) = o8;
    }
}

// graph pooling: 4 waves per graph, row-split + LDS reduce (f32 in, bf16 out)
__global__ __launch_bounds__(256) void pool_kernel(const float* __restrict__ x, const int* __restrict__ batch,
                                                   short* __restrict__ Gbf) {
    int g = blockIdx.x;
    int lo = 0, hi = N_NODES;
    while (lo < hi) { int mid = (lo + hi) >> 1; if (batch[mid] < g) lo = mid + 1; else hi = mid; }
    int s = lo;
    hi = N_NODES;
    while (lo < hi) { int mid = (lo + hi) >> 1; if (batch[mid] < g + 1) lo = mid + 1; else hi = mid; }
    int e = lo;
    const int wv = threadIdx.x >> 6;
    const int lane = threadIdx.x & 63;
    float acc[8] = {0, 0, 0, 0, 0, 0, 0, 0};
    for (int r = s + wv; r < e; r += 4) {
        const float* rp = x + (long)r * D + lane * 8;
        float4 v0 = *(const float4*)rp;
        float4 v1 = *(const float4*)(rp + 4);
        acc[0] += v0.x; acc[1] += v0.y; acc[2] += v0.z; acc[3] += v0.w;
        acc[4] += v1.x; acc[5] += v1.y; acc[6] += v1.z; acc[7] += v1.w;
    }
    __shared__ float red[4][512];
    #pragma unroll
    for (int k = 0; k < 8; k++) red[wv][lane * 8 + k] = acc[k];
    __syncthreads();
    if (wv == 0) {
        const float invc = 1.0f / fmaxf((float)(e - s), 1.0f);
        short8 o;
        #pragma unroll
        for (int k = 0; k < 8; k++) {
            float v = red[0][lane * 8 + k] + red[1][lane * 8 + k]
                    + red[2][lane * 8 + k] + red[3][lane * 8 + k];
            o[k] = f2bf(v * invc);
        }
        *(short8*)(Gbf + (long)g * D + lane * 8) = o;
    }
}

extern "C" void kernel_launch(void* const* d_in, const int* in_sizes, int n_in,
                              void* d_out, int out_size, void* d_ws, size_t ws_size,
                              hipStream_t stream) {
    (void)in_sizes; (void)n_in; (void)out_size; (void)ws_size;
    const float* nf    = (const float*)d_in[0];
    const int*   nidx  = (const int*)d_in[1];
    const int*   hidx  = (const int*)d_in[2];
    const int*   htype = (const int*)d_in[3];
    const int*   batch = (const int*)d_in[4];
    const float* in_w  = (const float*)d_in[6];
    const float* in_b  = (const float*)d_in[7];
    const float* temb  = (const float*)d_in[8];
    const float* l1w   = (const float*)d_in[9];
    const float* l1b   = (const float*)d_in[10];
    const float* l2w   = (const float*)d_in[11];
    const float* l2b   = (const float*)d_in[12];
    const float* lng   = (const float*)d_in[13];
    const float* lnb   = (const float*)d_in[14];
    const float* outw  = (const float*)d_in[15];
    const float* outb  = (const float*)d_in[16];

    float* out_graph = (float*)d_out;                       // [1024,512]
    float* out_nodes = out_graph + (long)N_GRAPHS * D;      // [100000,512]
    float* out_batch = out_nodes + (long)N_NODES * D;       // [100000]

    char* wsb = (char*)d_ws;
    size_t off = 0;
    auto alloc = [&](size_t bytes) {
        void* p = wsb + off;
        off += (bytes + 255) & ~(size_t)255;
        return p;
    };
    short* x_bf  = (short*)alloc((size_t)NPAD * D * 2);
    short* hs_bf = (short*)alloc((size_t)HPAD * D * 2);
    short* h_bf  = (short*)alloc((size_t)HPAD * D * 2);
    short* hs0   = (short*)alloc((size_t)HPAD * KPAD_IN * 2);
    short* G_bf  = (short*)alloc((size_t)N_GRAPHS * D * 2);
    short* A0    = (short*)alloc((size_t)NPAD * KPAD_IN * 2);
    short* wt    = (short*)alloc((size_t)D * D * 2);
    short* wt3   = (short*)alloc((size_t)3 * D * D * 2);
    short* w1bf  = (short*)alloc((size_t)3 * D * D * 2);
    short* W12t  = (short*)alloc((size_t)3 * D * D * 2);
    short* inwbf = (short*)alloc((size_t)256 * D * 2);
    short* M0t   = (short*)alloc((size_t)D * KPAD_IN * 2);
    float* TB    = (float*)alloc((size_t)3 * 4 * D * 4);
    float* tmpv  = (float*)alloc((size_t)D * 4);
    float* bb0   = (float*)alloc((size_t)D * 4);
    int* cnt_h   = (int*)alloc((size_t)N_HEDGES * 4);
    int* cnt_n   = (int*)alloc((size_t)N_NODES * 4);
    int* hoff    = (int*)alloc((size_t)(N_HEDGES + 1) * 4);
    int* noff    = (int*)alloc((size_t)(N_NODES + 1) * 4);
    int* hlist   = (int*)alloc((size_t)N_INC * 4);
    int* nlist   = (int*)alloc((size_t)N_INC * 4);
    int* bsumH   = (int*)alloc((size_t)256 * 4);
    int* bsumN   = (int*)alloc((size_t)256 * 4);

    // ---- build CSR (both directions); batchf fused into count ----
    hipMemsetAsync(cnt_h, 0, (size_t)N_HEDGES * 4, stream);
    hipMemsetAsync(cnt_n, 0, (size_t)N_NODES * 4, stream);
    count_inc_kernel<<<(N_INC + 255) / 256, 256, 0, stream>>>(nidx, hidx, batch, cnt_n, cnt_h, out_batch);
    const int NBH = (N_HEDGES + 2047) / 2048;
    const int NBN = (N_NODES + 2047) / 2048;
    scan1_kernel<<<NBH, 256, 0, stream>>>(cnt_h, hoff, bsumH, N_HEDGES);
    scan1_kernel<<<NBN, 256, 0, stream>>>(cnt_n, noff, bsumN, N_NODES);
    scan2both_kernel<<<2, 256, 0, stream>>>(bsumH, NBH, hoff + N_HEDGES, bsumN, NBN, noff + N_NODES);
    scan3_kernel<<<NBH, 256, 0, stream>>>(hoff, bsumH, N_HEDGES);
    scan3_kernel<<<NBN, 256, 0, stream>>>(noff, bsumN, N_NODES);
    place_kernel<<<(N_INC + 255) / 256, 256, 0, stream>>>(nidx, hidx, hoff, noff, cnt_h, cnt_n, hlist, nlist);

    // ---- weight precompute (batched): W12t[i] = (l1_w[i] @ l2_w[i])^T ; TB[i] ----
    cvt_f32_bf16_kernel<<<(3 * D * D / 8) / 256, 256, 0, stream>>>(l1w, w1bf);
    wtrans3_kernel<<<3 * D, 64, 0, stream>>>(l2w, wt3);
    gemm_bf16<<<24, 512, 0, stream>>>(w1bf, wt3, nullptr, nullptr, nullptr, W12t, D,
                                      nullptr, nullptr, nullptr, nullptr, D, 4,
                                      8, (long)D * D, (long)D * D, (long)D * D);
    smallmm3_kernel<<<6, 256, 0, stream>>>(temb, l1b, l2w, TB);

    // ---- layer-0 shortcut: M0t = (in_w @ W12[0])^T (K=64-packed); bb0 = (in_b@l1w0)@l2w0 + b1W2_0 ----
    cvt_w_pad_kernel<<<256, 64, 0, stream>>>(in_w, inwbf, D_IN);
    gemm_bf16<<<4, 512, 0, stream>>>(inwbf, W12t, nullptr, nullptr, nullptr, M0t, KPAD_IN,
                                     nullptr, nullptr, nullptr, nullptr, D, 4, 0, 0, 0, 0);
    vecmat_kernel<<<2, 256, 0, stream>>>(in_b, l1w, tmpv);
    vecmat_add_kernel<<<2, 256, 0, stream>>>(tmpv, l2w, TB + 3 * D, bb0);

    // ---- input projection: x_bf = bf16(nf @ in_w + in_b) ----
    wtrans_kernel<<<D, 64, 0, stream>>>(in_w, wt, D_IN, KPAD_IN);
    cvt_in_kernel<<<NPAD, 64, 0, stream>>>(nf, A0);
    const int NWG  = (NPAD / 256) * 4;   // 1564
    const int NWGH = (HPAD / 256) * 4;   // 784
    gemm_bf16<<<NWG, 512, 0, stream>>>(A0, wt, in_b, x_bf, nullptr, nullptr, 0,
                                       nullptr, nullptr, nullptr, nullptr, KPAD_IN, 4, 0, 0, 0, 0);

    for (int i = 0; i < 3; i++) {
        // hedge pre-sum (Ah·x), then hedge-space GEMM with fused message epilogue
        if (i == 0) {
            hedge_sum64_kernel<<<HPAD / 4, 256, 0, stream>>>(A0, hoff, hlist, hs0);
            gemm_bf16<<<NWGH, 512, 0, stream>>>(hs0, M0t, nullptr, h_bf, nullptr, nullptr, 0,
                                                hoff, htype, TB, bb0, KPAD_IN, 4, 0, 0, 0, 0);
        } else {
            hedge_sum_kernel<<<HPAD / 4, 256, 0, stream>>>(x_bf, hoff, hlist, hs_bf);
            gemm_bf16<<<NWGH, 512, 0, stream>>>(hs_bf, W12t + (size_t)i * D * D, nullptr,
                                                h_bf, nullptr, nullptr, 0,
                                                hoff, htype, TB + (size_t)i * 4 * D,
                                                TB + (size_t)i * 4 * D + 3 * D, D, 4, 0, 0, 0, 0);
        }
        // x = fast_gelu(LN(segsum(h)/clip + x + b2)); last layer writes ONLY f32 out_nodes
        node_ln_gelu_kernel<<<N_NODES / 4, 256, 0, stream>>>(h_bf, noff, nlist, x_bf,
                                                             l2b + (size_t)i * D,
                                                             lng + (size_t)i * D, lnb + (size_t)i * D,
                                                             (i < 2) ? nullptr : out_nodes);
    }

    // ---- graph pooling (reads f32 out_nodes) + output projection ----
    pool_kernel<<<N_GRAPHS, 256, 0, stream>>>(out_nodes, batch, G_bf);
    wtrans_kernel<<<D, 64, 0, stream>>>(outw, wt, D, D);
    gemm_bf16<<<(N_GRAPHS / 256) * 4, 512, 0, stream>>>(G_bf, wt, outb, nullptr, out_graph, nullptr, 0,
                                                        nullptr, nullptr, nullptr, nullptr, D, 4, 0, 0, 0, 0);
}

// Round 17
// 828.481 us; speedup vs baseline: 1.0864x; 1.0250x over previous
//
#include <hip/hip_runtime.h>
#include <math.h>

#define N_NODES  100000
#define N_HEDGES 50000
#define HPAD     50176    // 196 * 256
#define N_INC    300000
#define N_GRAPHS 1024
#define D_IN     49
#define D        512
#define NPAD     100096   // 391 * 256
#define KPAD_IN  64

typedef __attribute__((ext_vector_type(8))) short short8;
typedef __attribute__((ext_vector_type(8))) __bf16 bf16x8;
typedef __attribute__((ext_vector_type(4))) float f32x4;

__device__ __forceinline__ short f2bf(float f) {
    union { float f; unsigned u; } v; v.f = f;
    unsigned r = v.u + 0x7fffu + ((v.u >> 16) & 1u);
    return (short)(r >> 16);
}
__device__ __forceinline__ float bf2f(short s) {
    union { unsigned u; float f; } v; v.u = ((unsigned)(unsigned short)s) << 16;
    return v.f;
}

// fast tanh-form GELU (|err| <= ~1e-3 abs; threshold 20.48)
__device__ __forceinline__ float fast_gelu(float y) {
    const float y2 = y * y;
    const float p  = fmaf(y2, 0.0356774081f, 0.7978845608f);
    float arg = y * p * 2.8853900818f;
    arg = fminf(fmaxf(arg, -30.0f), 30.0f);
    const float u = __builtin_exp2f(arg);
    return y * u * __builtin_amdgcn_rcpf(1.0f + u);
}

__device__ __forceinline__ void gld16(const void* g, void* l) {
    __builtin_amdgcn_global_load_lds(
        (const __attribute__((address_space(1))) unsigned int*)g,
        (__attribute__((address_space(3))) unsigned int*)l, 16, 0, 0);
}

// ---------------- GEMM: C[M,512] = A[M,K](bf16) @ Bt[512,K](bf16), flexible epilogues --------------
// 256x128 tile, 8 waves. global_load_lds(16B) staging, pre-swizzled source. 2-buffer + counted
// vmcnt(3). 48KB LDS -> 3 blocks/CU. Builtin MFMA.
// Hedge mode (hoffp != null): cnt = hoffp[row+1]-hoffp[row]; v=(acc+cnt*bb)/clip(cnt)+tembW2[type].
__global__ __launch_bounds__(512) void gemm_bf16(
    const short* __restrict__ A, const short* __restrict__ Bt,
    const float* __restrict__ bias,
    short* __restrict__ Cbf, float* __restrict__ Cf, short* __restrict__ CbfT, int strideT,
    const int* __restrict__ hoffp, const int* __restrict__ htypes,
    const float* __restrict__ tembW2, const float* __restrict__ bb,
    int K, int nby, int layerWGs, long aStr, long bStr, long cStr)
{
    __shared__ short lds[24576];          // As: 2x256x32 @0 ; Bs: 2x128x32 @16384 ; epilogue overlay @0
    const int tid  = threadIdx.x;
    const int lane = tid & 63;
    const int wave = tid >> 6;
    const int wr = wave >> 1;
    const int wc = wave & 1;

    // bijective XCD-aware swizzle (m204)
    const int nwg = gridDim.x;
    const int q8 = nwg >> 3, r8 = nwg & 7;
    const int xcd = blockIdx.x & 7, loc = blockIdx.x >> 3;
    int wg = (xcd < r8) ? (xcd * (q8 + 1) + loc) : (r8 * (q8 + 1) + (xcd - r8) * q8 + loc);
    if (layerWGs) {
        const int layer = wg / layerWGs;
        wg %= layerWGs;
        A += layer * aStr;
        Bt += layer * bStr;
        if (CbfT) CbfT += layer * cStr;
    }
    const long row0 = (long)(wg / nby) * 256;
    const int  col0 = (wg % nby) * 128;

    f32x4 acc[4][4];
    #pragma unroll
    for (int m = 0; m < 4; m++)
        #pragma unroll
        for (int n = 0; n < 4; n++)
            acc[m][n] = (f32x4)(0.0f);

    const int ch   = lane & 3;
    const int rofs = lane >> 2;
    const short* aSrc[2];
    const short* bSrc;
    #pragma unroll
    for (int j = 0; j < 2; j++) {
        const int rloc = (wave * 2 + j) * 16 + rofs;
        const int sw = (rloc >> 1) & 3;
        aSrc[j] = A + (row0 + rloc) * (long)K + (ch ^ sw) * 8;
    }
    {
        const int rlb = wave * 16 + rofs;
        const int swb = (rlb >> 1) & 3;
        bSrc = Bt + ((long)col0 + rlb) * K + (ch ^ swb) * 8;
    }

    const int ks = lane >> 4;
    const int rl = lane & 15;
    const int nk = K >> 5;

    gld16(aSrc[0], &lds[(wave * 2) * 16 * 32]);
    gld16(aSrc[1], &lds[(wave * 2 + 1) * 16 * 32]);
    gld16(bSrc,    &lds[16384 + wave * 16 * 32]);
    if (nk > 1) {
        gld16(aSrc[0] + 32, &lds[8192 + (wave * 2) * 16 * 32]);
        gld16(aSrc[1] + 32, &lds[8192 + (wave * 2 + 1) * 16 * 32]);
        gld16(bSrc    + 32, &lds[16384 + 4096 + wave * 16 * 32]);
    }

    for (int t = 0; t < nk; t++) {
        if (t + 1 < nk) asm volatile("s_waitcnt vmcnt(3)" ::: "memory");
        else            asm volatile("s_waitcnt vmcnt(0)" ::: "memory");
        __builtin_amdgcn_s_barrier();
        __builtin_amdgcn_sched_barrier(0);
        const int cb = t & 1;
        bf16x8 a[4], b[4];
        #pragma unroll
        for (int m = 0; m < 4; m++) {
            const int rr = wr * 64 + m * 16 + rl;
            a[m] = *(const bf16x8*)&lds[cb * 8192 + rr * 32 + (ks ^ ((rr >> 1) & 3)) * 8];
        }
        #pragma unroll
        for (int n = 0; n < 4; n++) {
            const int rr = wc * 64 + n * 16 + rl;
            b[n] = *(const bf16x8*)&lds[16384 + cb * 4096 + rr * 32 + (ks ^ ((rr >> 1) & 3)) * 8];
        }
        #pragma unroll
        for (int m = 0; m < 4; m++)
            #pragma unroll
            for (int n = 0; n < 4; n++)
                acc[m][n] = __builtin_amdgcn_mfma_f32_16x16x32_bf16(a[m], b[n], acc[m][n], 0, 0, 0);
        __builtin_amdgcn_sched_barrier(0);
        __builtin_amdgcn_s_barrier();
        if (t + 2 < nk) {
            gld16(aSrc[0] + (t + 2) * 32, &lds[cb * 8192 + (wave * 2) * 16 * 32]);
            gld16(aSrc[1] + (t + 2) * 32, &lds[cb * 8192 + (wave * 2 + 1) * 16 * 32]);
            gld16(bSrc    + (t + 2) * 32, &lds[16384 + cb * 4096 + wave * 16 * 32]);
        }
    }

    const int rl2 = lane & 15;
    if (Cbf && !Cf && !CbfT) {
        float bbv[4], tw0[4], tw1[4], tw2[4], biv[4];
        #pragma unroll
        for (int n = 0; n < 4; n++) {
            const int col = col0 + wc * 64 + n * 16 + rl2;
            if (hoffp) {
                bbv[n] = bb[col];
                tw0[n] = tembW2[col];
                tw1[n] = tembW2[D + col];
                tw2[n] = tembW2[2 * D + col];
            } else {
                biv[n] = bias ? bias[col] : 0.0f;
            }
        }
        short* ep = &lds[wave * 2304];
        #pragma unroll
        for (int p = 0; p < 2; p++) {
            #pragma unroll
            for (int mm = 0; mm < 2; mm++) {
                const int m = 2 * p + mm;
                #pragma unroll
                for (int rr = 0; rr < 4; rr++) {
                    const long row = row0 + wr * 64 + m * 16 + (lane >> 4) * 4 + rr;
                    const int  lr  = mm * 16 + (lane >> 4) * 4 + rr;
                    if (hoffp) {
                        const bool valid = row < N_HEDGES;
                        const float cf  = valid ? (float)(hoffp[row + 1] - hoffp[row]) : 0.0f;
                        const float icf = 1.0f / fmaxf(cf, 1.0f);
                        const int ty = valid ? htypes[row] : 0;
                        #pragma unroll
                        for (int n = 0; n < 4; n++) {
                            float tsel = (ty == 0) ? tw0[n] : (ty == 1) ? tw1[n] : tw2[n];
                            float v = (acc[m][n][rr] + cf * bbv[n]) * icf + tsel;
                            ep[lr * 72 + n * 16 + rl2] = f2bf(v);
                        }
                    } else {
                        #pragma unroll
                        for (int n = 0; n < 4; n++) {
                            float v = acc[m][n][rr] + biv[n];
                            ep[lr * 72 + n * 16 + rl2] = f2bf(v);
                        }
                    }
                }
            }
            __syncthreads();
            #pragma unroll
            for (int i = 0; i < 4; i++) {
                const int lr2 = i * 8 + (lane >> 3);
                const int c2  = lane & 7;
                short8 vv = *(const short8*)&ep[lr2 * 72 + c2 * 8];
                const long row = row0 + wr * 64 + p * 32 + lr2;
                *(short8*)&Cbf[row * D + col0 + wc * 64 + c2 * 8] = vv;
            }
            __syncthreads();
        }
    } else {
        const int rb4 = wr * 64 + (lane >> 4) * 4;
        #pragma unroll
        for (int m = 0; m < 4; m++) {
            #pragma unroll
            for (int n = 0; n < 4; n++) {
                const int col = col0 + wc * 64 + n * 16 + rl2;
                const float bi = bias ? bias[col] : 0.0f;
                #pragma unroll
                for (int rr = 0; rr < 4; rr++) {
                    const long row = row0 + rb4 + m * 16 + rr;
                    float v = acc[m][n][rr];
                    if (hoffp) {
                        const bool valid = row < N_HEDGES;
                        const float cf = valid ? (float)(hoffp[row + 1] - hoffp[row]) : 0.0f;
                        const int ty = valid ? htypes[row] : 0;
                        v = (v + cf * bb[col]) * (1.0f / fmaxf(cf, 1.0f)) + tembW2[(long)ty * D + col];
                    } else {
                        v += bi;
                    }
                    if (Cbf)  Cbf[row * D + col] = f2bf(v);
                    if (Cf)   Cf[row * D + col]  = v;
                    if (CbfT && row < strideT) CbfT[(long)col * strideT + row] = f2bf(v);
                }
            }
        }
    }
}

// ---------------- degree counts + batch float output (fused) ----------------
__global__ void count_inc_kernel(const int* __restrict__ nidx, const int* __restrict__ hidx,
                                 const int* __restrict__ batch, int* cnt_n, int* cnt_h,
                                 float* __restrict__ ob) {
    int i = blockIdx.x * 256 + threadIdx.x;
    if (i < N_INC) {
        atomicAdd(&cnt_h[hidx[i]], 1);
        atomicAdd(&cnt_n[nidx[i]], 1);
    }
    if (i < N_NODES) ob[i] = (float)batch[i];
}

// ---------------- hierarchical exclusive scan (3 phases, 2048 elems/block) ----------------
__global__ __launch_bounds__(256) void scan1_kernel(const int* __restrict__ cnt, int* __restrict__ out,
                                                    int* __restrict__ bsum, int n) {
    __shared__ int s[256];
    const int t = threadIdx.x;
    const long base = (long)blockIdx.x * 2048 + t * 8;
    int v[8];
    int ts = 0;
    #pragma unroll
    for (int j = 0; j < 8; j++) {
        v[j] = (base + j < n) ? cnt[base + j] : 0;
        ts += v[j];
    }
    s[t] = ts;
    __syncthreads();
    for (int ofs = 1; ofs < 256; ofs <<= 1) {
        int x = (t >= ofs) ? s[t - ofs] : 0;
        __syncthreads();
        s[t] += x;
        __syncthreads();
    }
    int run = (t == 0) ? 0 : s[t - 1];
    #pragma unroll
    for (int j = 0; j < 8; j++) {
        if (base + j < n) out[base + j] = run;
        run += v[j];
    }
    if (t == 255) bsum[blockIdx.x] = s[255];
}

// scan both block-sum arrays in one dispatch
__global__ __launch_bounds__(256) void scan2both_kernel(int* __restrict__ bsumA, int nA, int* __restrict__ totalA,
                                                        int* __restrict__ bsumB, int nB, int* __restrict__ totalB) {
    int* bsum = blockIdx.x ? bsumB : bsumA;
    int  nb   = blockIdx.x ? nB : nA;
    int* total = blockIdx.x ? totalB : totalA;
    __shared__ int s[256];
    const int t = threadIdx.x;
    int v = (t < nb) ? bsum[t] : 0;
    s[t] = v;
    __syncthreads();
    for (int ofs = 1; ofs < 256; ofs <<= 1) {
        int x = (t >= ofs) ? s[t - ofs] : 0;
        __syncthreads();
        s[t] += x;
        __syncthreads();
    }
    if (t < nb) bsum[t] = (t == 0) ? 0 : s[t - 1];
    if (t == 255) *total = s[255];
}

__global__ __launch_bounds__(256) void scan3_kernel(int* __restrict__ out, const int* __restrict__ bsum, int n) {
    const int add = bsum[blockIdx.x];
    if (add == 0) return;
    const long base = (long)blockIdx.x * 2048 + threadIdx.x * 8;
    #pragma unroll
    for (int j = 0; j < 8; j++)
        if (base + j < n) out[base + j] += add;
}

// CSR placement; consumes cnt arrays as cursors via atomicSub
__global__ void place_kernel(const int* __restrict__ nidx, const int* __restrict__ hidx,
                             const int* __restrict__ hoff, const int* __restrict__ noff,
                             int* cnt_h, int* cnt_n, int* __restrict__ hlist, int* __restrict__ nlist) {
    int e = blockIdx.x * 256 + threadIdx.x;
    if (e < N_INC) {
        int h = hidx[e], n = nidx[e];
        int p = atomicSub(&cnt_h[h], 1) - 1;
        hlist[hoff[h] + p] = n;
        int q = atomicSub(&cnt_n[n], 1) - 1;
        nlist[noff[n] + q] = h;
    }
}

// ---------------- weight transpose+convert: W[K,512] f32 -> Wt[512,Kpad] bf16 ----------------
__global__ void wtrans_kernel(const float* __restrict__ W, short* __restrict__ Wt, int K, int Kpad) {
    int n = blockIdx.x;
    for (int k = threadIdx.x; k < Kpad; k += 64)
        Wt[(long)n * Kpad + k] = (k < K) ? f2bf(W[(long)k * D + n]) : (short)0;
}

// batched l2w transpose: 3 layers in one dispatch (grid 3*D)
__global__ void wtrans3_kernel(const float* __restrict__ W, short* __restrict__ Wt) {
    int layer = blockIdx.x >> 9;
    int n = blockIdx.x & 511;
    const float* src = W + (size_t)layer * D * D;
    short* dst = Wt + (size_t)layer * D * D;
    for (int k = threadIdx.x; k < D; k += 64)
        dst[(long)n * D + k] = f2bf(src[(long)k * D + n]);
}

// plain f32 -> bf16 convert (8/thread)
__global__ void cvt_f32_bf16_kernel(const float* __restrict__ src, short* __restrict__ dst) {
    long i = ((long)blockIdx.x * 256 + threadIdx.x) * 8;
    float4 f0 = *(const float4*)(src + i);
    float4 f1 = *(const float4*)(src + i + 4);
    short8 o;
    o[0] = f2bf(f0.x); o[1] = f2bf(f0.y); o[2] = f2bf(f0.z); o[3] = f2bf(f0.w);
    o[4] = f2bf(f1.x); o[5] = f2bf(f1.y); o[6] = f2bf(f1.z); o[7] = f2bf(f1.w);
    *(short8*)(dst + i) = o;
}

// W[rows,512] f32 -> dst[256,512] bf16, zero-padding rows >= rows_real
__global__ void cvt_w_pad_kernel(const float* __restrict__ src, short* __restrict__ dst, int rows_real) {
    int r = blockIdx.x;
    int c = threadIdx.x * 8;
    short8 o = (short8)0;
    if (r < rows_real) {
        float4 f0 = *(const float4*)(src + (long)r * D + c);
        float4 f1 = *(const float4*)(src + (long)r * D + c + 4);
        o[0] = f2bf(f0.x); o[1] = f2bf(f0.y); o[2] = f2bf(f0.z); o[3] = f2bf(f0.w);
        o[4] = f2bf(f1.x); o[5] = f2bf(f1.y); o[6] = f2bf(f1.z); o[7] = f2bf(f1.w);
    }
    *(short8*)(dst + (long)r * D + c) = o;
}

// vecmat: out[col] = sum_j v[j] * M[j*512+col]
__global__ __launch_bounds__(256) void vecmat_kernel(const float* __restrict__ v,
                                                     const float* __restrict__ M,
                                                     float* __restrict__ out) {
    int col = blockIdx.x * 256 + threadIdx.x;
    float a = 0.f;
    for (int j = 0; j < D; j++) a += v[j] * M[(long)j * D + col];
    out[col] = a;
}

// vecmat + add
__global__ __launch_bounds__(256) void vecmat_add_kernel(const float* __restrict__ v,
                                                         const float* __restrict__ M,
                                                         const float* __restrict__ addv,
                                                         float* __restrict__ out) {
    int col = blockIdx.x * 256 + threadIdx.x;
    float a = addv[col];
    for (int j = 0; j < D; j++) a += v[j] * M[(long)j * D + col];
    out[col] = a;
}

// batched TB precompute: grid 6 (3 layers x 2 col-halves). TB[layer][4][512]
__global__ __launch_bounds__(256) void smallmm3_kernel(
    const float* __restrict__ temb, const float* __restrict__ l1b,
    const float* __restrict__ l2w, float* __restrict__ TB)
{
    int layer = blockIdx.x >> 1;
    int col = (blockIdx.x & 1) * 256 + threadIdx.x;
    const float* b1 = l1b + (size_t)layer * D;
    const float* W2 = l2w + (size_t)layer * D * D;
    float a0 = 0.f, a1 = 0.f, a2 = 0.f, a3 = 0.f;
    for (int j = 0; j < D; j++) {
        float w = W2[(long)j * D + col];
        a0 += temb[j] * w;
        a1 += temb[D + j] * w;
        a2 += temb[2 * D + j] * w;
        a3 += b1[j] * w;
    }
    float* o = TB + (size_t)layer * 4 * D;
    o[col] = a0; o[D + col] = a1; o[2 * D + col] = a2; o[3 * D + col] = a3;
}

// node_features [N,49] f32 -> A0 [NPAD,64] bf16 (zero pad); flattened 256-thr grid
__global__ __launch_bounds__(256) void cvt_in_kernel(const float* __restrict__ nf, short* __restrict__ A0) {
    long i = (long)blockIdx.x * 256 + threadIdx.x;     // over NPAD*64
    int r = (int)(i >> 6), c = (int)(i & 63);
    short v = 0;
    if (r < N_NODES && c < D_IN) v = f2bf(nf[(long)r * D_IN + c]);
    A0[i] = v;
}

// hedge pre-sum, 512 cols (unrolled x2 gather): hs[e,:] = sum_{members} x[n,:]
__global__ __launch_bounds__(256) void hedge_sum_kernel(
    const short* __restrict__ x, const int* __restrict__ hoff, const int* __restrict__ hlist,
    short* __restrict__ hs)
{
    int row = blockIdx.x * 4 + (threadIdx.x >> 6);
    int lane = threadIdx.x & 63;
    float acc[8] = {0, 0, 0, 0, 0, 0, 0, 0};
    if (row < N_HEDGES) {
        int s = hoff[row], e = hoff[row + 1];
        int j = s;
        for (; j + 1 < e; j += 2) {
            short8 v0 = *(const short8*)(x + (long)hlist[j] * D + lane * 8);
            short8 v1 = *(const short8*)(x + (long)hlist[j + 1] * D + lane * 8);
            #pragma unroll
            for (int k = 0; k < 8; k++) acc[k] += bf2f(v0[k]) + bf2f(v1[k]);
        }
        if (j < e) {
            short8 v0 = *(const short8*)(x + (long)hlist[j] * D + lane * 8);
            #pragma unroll
            for (int k = 0; k < 8; k++) acc[k] += bf2f(v0[k]);
        }
    }
    short8 o;
    #pragma unroll
    for (int k = 0; k < 8; k++) o[k] = f2bf(acc[k]);
    *(short8*)(hs + (long)row * D + lane * 8) = o;
}

// hedge pre-sum, 64 cols — VECTORIZED: 8 rows/wave, lane = (row-in-group, 8-col chunk), short8 loads
__global__ __launch_bounds__(256) void hedge_sum64_kernel(
    const short* __restrict__ A0, const int* __restrict__ hoff, const int* __restrict__ hlist,
    short* __restrict__ hs0)
{
    const int wv   = threadIdx.x >> 6;
    const int lane = threadIdx.x & 63;
    const int row  = blockIdx.x * 32 + wv * 8 + (lane >> 3);   // grid = HPAD/32
    const int c8   = (lane & 7) * 8;
    float acc[8] = {0, 0, 0, 0, 0, 0, 0, 0};
    if (row < N_HEDGES) {
        int s = hoff[row], e = hoff[row + 1];
        for (int j = s; j < e; j++) {
            short8 v = *(const short8*)(A0 + (long)hlist[j] * KPAD_IN + c8);
            #pragma unroll
            for (int k = 0; k < 8; k++) acc[k] += bf2f(v[k]);
        }
    }
    short8 o;
    #pragma unroll
    for (int k = 0; k < 8; k++) o[k] = f2bf(acc[k]);
    *(short8*)(hs0 + (long)row * KPAD_IN + c8) = o;
}

// fused node gather + residual + bias + LayerNorm + fast GELU.
__global__ __launch_bounds__(256) void node_ln_gelu_kernel(
    const short* __restrict__ hmsg, const int* __restrict__ noff, const int* __restrict__ nlist,
    short* __restrict__ x, const float* __restrict__ b2,
    const float* __restrict__ g, const float* __restrict__ b, float* __restrict__ outf)
{
    const int row = blockIdx.x * 4 + (threadIdx.x >> 6);
    const int lane = threadIdx.x & 63;
    int s = noff[row], e = noff[row + 1];
    float acc[8] = {0, 0, 0, 0, 0, 0, 0, 0};
    int j = s;
    for (; j + 1 < e; j += 2) {
        short8 v0 = *(const short8*)(hmsg + (long)nlist[j] * D + lane * 8);
        short8 v1 = *(const short8*)(hmsg + (long)nlist[j + 1] * D + lane * 8);
        #pragma unroll
        for (int k = 0; k < 8; k++) acc[k] += bf2f(v0[k]) + bf2f(v1[k]);
    }
    if (j < e) {
        short8 v0 = *(const short8*)(hmsg + (long)nlist[j] * D + lane * 8);
        #pragma unroll
        for (int k = 0; k < 8; k++) acc[k] += bf2f(v0[k]);
    }
    const float inv = 1.0f / fmaxf((float)(e - s), 1.0f);
    short8 xv = *(const short8*)(x + (long)row * D + lane * 8);
    const float4 c0 = *(const float4*)(b2 + lane * 8);
    const float4 c1 = *(const float4*)(b2 + lane * 8 + 4);
    const float cv[8] = {c0.x, c0.y, c0.z, c0.w, c1.x, c1.y, c1.z, c1.w};
    float f[8];
    float sum = 0.f, sq = 0.f;
    #pragma unroll
    for (int k = 0; k < 8; k++) {
        f[k] = acc[k] * inv + bf2f(xv[k]) + cv[k];
        sum += f[k]; sq += f[k] * f[k];
    }
    #pragma unroll
    for (int o = 32; o > 0; o >>= 1) { sum += __shfl_xor(sum, o, 64); sq += __shfl_xor(sq, o, 64); }
    const float mean = sum * (1.0f / D);
    const float var  = sq * (1.0f / D) - mean * mean;
    const float rstd = rsqrtf(var + 1e-5f);
    const float4 g0 = *(const float4*)(g + lane * 8);
    const float4 g1 = *(const float4*)(g + lane * 8 + 4);
    const float4 b0 = *(const float4*)(b + lane * 8);
    const float4 b1 = *(const float4*)(b + lane * 8 + 4);
    const float gv[8] = {g0.x, g0.y, g0.z, g0.w, g1.x, g1.y, g1.z, g1.w};
    const float bv[8] = {b0.x, b0.y, b0.z, b0.w, b1.x, b1.y, b1.z, b1.w};
    float yout[8];
    #pragma unroll
    for (int k = 0; k < 8; k++) {
        float y = (f[k] - mean) * rstd * gv[k] + bv[k];
        yout[k] = fast_gelu(y);
    }
    if (outf) {
        float4 o0 = {yout[0], yout[1], yout[2], yout[3]};
        float4 o1 = {yout[4], yout[5], yout[6], yout[7]};
        *(float4*)(outf + (long)row * D + lane * 8) = o0;
        *(float4*)(outf + (long)row * D + lane * 8 + 4) = o1;
    } else {
        short8 o8;
        #pragma unroll
        for (int k = 0; k < 8; k++) o8[k] = f2bf(yout[k]);
        *(short8*)(x + (long)row * D + lane * 8) = o8;
    }
}

// graph pooling: 4 waves per graph, row-split + LDS reduce (f32 in, bf16 out)
__global__ __launch_bounds__(256) void pool_kernel(const float* __restrict__ x, const int* __restrict__ batch,
                                                   short* __restrict__ Gbf) {
    int g = blockIdx.x;
    int lo = 0, hi = N_NODES;
    while (lo < hi) { int mid = (lo + hi) >> 1; if (batch[mid] < g) lo = mid + 1; else hi = mid; }
    int s = lo;
    hi = N_NODES;
    while (lo < hi) { int mid = (lo + hi) >> 1; if (batch[mid] < g + 1) lo = mid + 1; else hi = mid; }
    int e = lo;
    const int wv = threadIdx.x >> 6;
    const int lane = threadIdx.x & 63;
    float acc[8] = {0, 0, 0, 0, 0, 0, 0, 0};
    for (int r = s + wv; r < e; r += 4) {
        const float* rp = x + (long)r * D + lane * 8;
        float4 v0 = *(const float4*)rp;
        float4 v1 = *(const float4*)(rp + 4);
        acc[0] += v0.x; acc[1] += v0.y; acc[2] += v0.z; acc[3] += v0.w;
        acc[4] += v1.x; acc[5] += v1.y; acc[6] += v1.z; acc[7] += v1.w;
    }
    __shared__ float red[4][512];
    #pragma unroll
    for (int k = 0; k < 8; k++) red[wv][lane * 8 + k] = acc[k];
    __syncthreads();
    if (wv == 0) {
        const float invc = 1.0f / fmaxf((float)(e - s), 1.0f);
        short8 o;
        #pragma unroll
        for (int k = 0; k < 8; k++) {
            float v = red[0][lane * 8 + k] + red[1][lane * 8 + k]
                    + red[2][lane * 8 + k] + red[3][lane * 8 + k];
            o[k] = f2bf(v * invc);
        }
        *(short8*)(Gbf + (long)g * D + lane * 8) = o;
    }
}

extern "C" void kernel_launch(void* const* d_in, const int* in_sizes, int n_in,
                              void* d_out, int out_size, void* d_ws, size_t ws_size,
                              hipStream_t stream) {
    (void)in_sizes; (void)n_in; (void)out_size; (void)ws_size;
    const float* nf    = (const float*)d_in[0];
    const int*   nidx  = (const int*)d_in[1];
    const int*   hidx  = (const int*)d_in[2];
    const int*   htype = (const int*)d_in[3];
    const int*   batch = (const int*)d_in[4];
    const float* in_w  = (const float*)d_in[6];
    const float* in_b  = (const float*)d_in[7];
    const float* temb  = (const float*)d_in[8];
    const float* l1w   = (const float*)d_in[9];
    const float* l1b   = (const float*)d_in[10];
    const float* l2w   = (const float*)d_in[11];
    const float* l2b   = (const float*)d_in[12];
    const float* lng   = (const float*)d_in[13];
    const float* lnb   = (const float*)d_in[14];
    const float* outw  = (const float*)d_in[15];
    const float* outb  = (const float*)d_in[16];

    float* out_graph = (float*)d_out;                       // [1024,512]
    float* out_nodes = out_graph + (long)N_GRAPHS * D;      // [100000,512]
    float* out_batch = out_nodes + (long)N_NODES * D;       // [100000]

    char* wsb = (char*)d_ws;
    size_t off = 0;
    auto alloc = [&](size_t bytes) {
        void* p = wsb + off;
        off += (bytes + 255) & ~(size_t)255;
        return p;
    };
    short* x_bf  = (short*)alloc((size_t)NPAD * D * 2);
    short* hs_bf = (short*)alloc((size_t)HPAD * D * 2);
    short* h_bf  = (short*)alloc((size_t)HPAD * D * 2);
    short* hs0   = (short*)alloc((size_t)HPAD * KPAD_IN * 2);
    short* G_bf  = (short*)alloc((size_t)N_GRAPHS * D * 2);
    short* A0    = (short*)alloc((size_t)NPAD * KPAD_IN * 2);
    short* wt    = (short*)alloc((size_t)D * D * 2);
    short* wt3   = (short*)alloc((size_t)3 * D * D * 2);
    short* w1bf  = (short*)alloc((size_t)3 * D * D * 2);
    short* W12t  = (short*)alloc((size_t)3 * D * D * 2);
    short* inwbf = (short*)alloc((size_t)256 * D * 2);
    short* M0t   = (short*)alloc((size_t)D * KPAD_IN * 2);
    float* TB    = (float*)alloc((size_t)3 * 4 * D * 4);
    float* tmpv  = (float*)alloc((size_t)D * 4);
    float* bb0   = (float*)alloc((size_t)D * 4);
    int* cnt_h   = (int*)alloc((size_t)N_HEDGES * 4);
    int* cnt_n   = (int*)alloc((size_t)N_NODES * 4);
    int* hoff    = (int*)alloc((size_t)(N_HEDGES + 1) * 4);
    int* noff    = (int*)alloc((size_t)(N_NODES + 1) * 4);
    int* hlist   = (int*)alloc((size_t)N_INC * 4);
    int* nlist   = (int*)alloc((size_t)N_INC * 4);
    int* bsumH   = (int*)alloc((size_t)256 * 4);
    int* bsumN   = (int*)alloc((size_t)256 * 4);

    // ---- build CSR (both directions); batchf fused into count ----
    hipMemsetAsync(cnt_h, 0, (size_t)N_HEDGES * 4, stream);
    hipMemsetAsync(cnt_n, 0, (size_t)N_NODES * 4, stream);
    count_inc_kernel<<<(N_INC + 255) / 256, 256, 0, stream>>>(nidx, hidx, batch, cnt_n, cnt_h, out_batch);
    const int NBH = (N_HEDGES + 2047) / 2048;
    const int NBN = (N_NODES + 2047) / 2048;
    scan1_kernel<<<NBH, 256, 0, stream>>>(cnt_h, hoff, bsumH, N_HEDGES);
    scan1_kernel<<<NBN, 256, 0, stream>>>(cnt_n, noff, bsumN, N_NODES);
    scan2both_kernel<<<2, 256, 0, stream>>>(bsumH, NBH, hoff + N_HEDGES, bsumN, NBN, noff + N_NODES);
    scan3_kernel<<<NBH, 256, 0, stream>>>(hoff, bsumH, N_HEDGES);
    scan3_kernel<<<NBN, 256, 0, stream>>>(noff, bsumN, N_NODES);
    place_kernel<<<(N_INC + 255) / 256, 256, 0, stream>>>(nidx, hidx, hoff, noff, cnt_h, cnt_n, hlist, nlist);

    // ---- weight precompute (batched): W12t[i] = (l1_w[i] @ l2_w[i])^T ; TB[i] ----
    cvt_f32_bf16_kernel<<<(3 * D * D / 8) / 256, 256, 0, stream>>>(l1w, w1bf);
    wtrans3_kernel<<<3 * D, 64, 0, stream>>>(l2w, wt3);
    gemm_bf16<<<24, 512, 0, stream>>>(w1bf, wt3, nullptr, nullptr, nullptr, W12t, D,
                                      nullptr, nullptr, nullptr, nullptr, D, 4,
                                      8, (long)D * D, (long)D * D, (long)D * D);
    smallmm3_kernel<<<6, 256, 0, stream>>>(temb, l1b, l2w, TB);

    // ---- layer-0 shortcut: M0t = (in_w @ W12[0])^T (K=64-packed); bb0 = (in_b@l1w0)@l2w0 + b1W2_0 ----
    cvt_w_pad_kernel<<<256, 64, 0, stream>>>(in_w, inwbf, D_IN);
    gemm_bf16<<<4, 512, 0, stream>>>(inwbf, W12t, nullptr, nullptr, nullptr, M0t, KPAD_IN,
                                     nullptr, nullptr, nullptr, nullptr, D, 4, 0, 0, 0, 0);
    vecmat_kernel<<<2, 256, 0, stream>>>(in_b, l1w, tmpv);
    vecmat_add_kernel<<<2, 256, 0, stream>>>(tmpv, l2w, TB + 3 * D, bb0);

    // ---- input projection: x_bf = bf16(nf @ in_w + in_b) ----
    wtrans_kernel<<<D, 64, 0, stream>>>(in_w, wt, D_IN, KPAD_IN);
    cvt_in_kernel<<<(NPAD * 64) / 256, 256, 0, stream>>>(nf, A0);
    const int NWG  = (NPAD / 256) * 4;   // 1564
    const int NWGH = (HPAD / 256) * 4;   // 784
    gemm_bf16<<<NWG, 512, 0, stream>>>(A0, wt, in_b, x_bf, nullptr, nullptr, 0,
                                       nullptr, nullptr, nullptr, nullptr, KPAD_IN, 4, 0, 0, 0, 0);

    for (int i = 0; i < 3; i++) {
        // hedge pre-sum (Ah·x), then hedge-space GEMM with fused message epilogue
        if (i == 0) {
            hedge_sum64_kernel<<<HPAD / 32, 256, 0, stream>>>(A0, hoff, hlist, hs0);
            gemm_bf16<<<NWGH, 512, 0, stream>>>(hs0, M0t, nullptr, h_bf, nullptr, nullptr, 0,
                                                hoff, htype, TB, bb0, KPAD_IN, 4, 0, 0, 0, 0);
        } else {
            hedge_sum_kernel<<<HPAD / 4, 256, 0, stream>>>(x_bf, hoff, hlist, hs_bf);
            gemm_bf16<<<NWGH, 512, 0, stream>>>(hs_bf, W12t + (size_t)i * D * D, nullptr,
                                                h_bf, nullptr, nullptr, 0,
                                                hoff, htype, TB + (size_t)i * 4 * D,
                                                TB + (size_t)i * 4 * D + 3 * D, D, 4, 0, 0, 0, 0);
        }
        // x = fast_gelu(LN(segsum(h)/clip + x + b2)); last layer writes ONLY f32 out_nodes
        node_ln_gelu_kernel<<<N_NODES / 4, 256, 0, stream>>>(h_bf, noff, nlist, x_bf,
                                                             l2b + (size_t)i * D,
                                                             lng + (size_t)i * D, lnb + (size_t)i * D,
                                                             (i < 2) ? nullptr : out_nodes);
    }

    // ---- graph pooling (reads f32 out_nodes) + output projection ----
    pool_kernel<<<N_GRAPHS, 256, 0, stream>>>(out_nodes, batch, G_bf);
    wtrans_kernel<<<D, 64, 0, stream>>>(outw, wt, D, D);
    gemm_bf16<<<(N_GRAPHS / 256) * 4, 512, 0, stream>>>(G_bf, wt, outb, nullptr, out_graph, nullptr, 0,
                                                        nullptr, nullptr, nullptr, nullptr, D, 4, 0, 0, 0, 0);
}